// Round 1
// baseline (978.143 us; speedup 1.0000x reference)
//
#include <hip/hip_runtime.h>
#include <math.h>

#define BATCH 2
#define SEQ   2048
#define HIDDEN 1024
#define HEADS 16
#define HD    64
// SCALE = 8.0 -> multiply q by 0.125 at store time

// ---------------------------------------------------------------------------
// Kernel 1: QKV projection. C[M=4096, N=3072] = X[M,1024] * W[N,1024]^T + b
// 64x64 tile, 256 threads, 4x4 acc per thread, K-tile 16, f32.
// Epilogue scatters into q_ws/k_ws/v_ws laid out [b][h][s][d] (q pre-scaled).
// ---------------------------------------------------------------------------
__global__ __launch_bounds__(256)
void qkv_proj(const float* __restrict__ X, const float* __restrict__ W,
              const float* __restrict__ bias,
              float* __restrict__ q_ws, float* __restrict__ k_ws,
              float* __restrict__ v_ws)
{
    __shared__ float As[16][68];   // [k][m]
    __shared__ float Bs[16][68];   // [k][n]
    const int t  = threadIdx.x;
    const int m0 = blockIdx.x * 64;
    const int n0 = blockIdx.y * 64;
    const int tr = t >> 4, tc = t & 15;
    const int lr = t >> 2;              // 0..63 load row
    const int lk = (t & 3) << 2;        // 0,4,8,12 load k
    float acc[4][4] = {};

    const float* Arow = X + (size_t)(m0 + lr) * HIDDEN + lk;
    const float* Brow = W + (size_t)(n0 + lr) * HIDDEN + lk;

    for (int k0 = 0; k0 < HIDDEN; k0 += 16) {
        float4 a = *(const float4*)(Arow + k0);
        float4 b = *(const float4*)(Brow + k0);
        __syncthreads();
        As[lk+0][lr] = a.x; As[lk+1][lr] = a.y; As[lk+2][lr] = a.z; As[lk+3][lr] = a.w;
        Bs[lk+0][lr] = b.x; Bs[lk+1][lr] = b.y; Bs[lk+2][lr] = b.z; Bs[lk+3][lr] = b.w;
        __syncthreads();
        #pragma unroll
        for (int k = 0; k < 16; ++k) {
            float4 av = *(const float4*)&As[k][tr << 2];
            float4 bv = *(const float4*)&Bs[k][tc << 2];
            float aa[4] = {av.x, av.y, av.z, av.w};
            float bb[4] = {bv.x, bv.y, bv.z, bv.w};
            #pragma unroll
            for (int i = 0; i < 4; ++i)
                #pragma unroll
                for (int j = 0; j < 4; ++j)
                    acc[i][j] = fmaf(aa[i], bb[j], acc[i][j]);
        }
    }

    // epilogue + scatter. Tile is 64-aligned in N, so one (which, head) per tile.
    const int o0    = n0 + (tc << 2);
    const int which = o0 >> 10;           // 0=q 1=k 2=v
    const int h     = (o0 & 1023) >> 6;
    const int d0    = o0 & 63;
    float* dst = (which == 0) ? q_ws : ((which == 1) ? k_ws : v_ws);
    const float scl = (which == 0) ? 0.125f : 1.0f;
    float4 bv = *(const float4*)&bias[o0];
    float bb[4] = {bv.x, bv.y, bv.z, bv.w};
    #pragma unroll
    for (int i = 0; i < 4; ++i) {
        int m = m0 + (tr << 2) + i;
        int b = m >> 11, s = m & 2047;
        float4 r;
        r.x = (acc[i][0] + bb[0]) * scl;
        r.y = (acc[i][1] + bb[1]) * scl;
        r.z = (acc[i][2] + bb[2]) * scl;
        r.w = (acc[i][3] + bb[3]) * scl;
        *(float4*)&dst[(((size_t)(b * HEADS + h)) * SEQ + s) * HD + d0] = r;
    }
}

// ---------------------------------------------------------------------------
// Kernel 2: flash attention, f32. One block per (qtile=64 rows, head, batch).
// K and V share one LDS buffer (K transposed for scores, V natural for PV).
// ---------------------------------------------------------------------------
__global__ __launch_bounds__(256)
void attn(const float* __restrict__ q_ws, const float* __restrict__ k_ws,
          const float* __restrict__ v_ws, float* __restrict__ ctx)
{
    __shared__ float Qs[64][68];    // [d][qr]
    __shared__ float KVs[64][68];   // K phase: [d][kc]; V phase: [kc][d]
    __shared__ float Pt[64][68];    // [kc][qr]
    __shared__ float red[64][16];
    __shared__ float mrow[64], lrow[64], fbuf[64];

    const int t  = threadIdx.x;
    const int q0 = blockIdx.x * 64;
    const int h  = blockIdx.y;
    const int b  = blockIdx.z;
    const size_t base = ((size_t)(b * HEADS + h)) * SEQ * HD;
    const int tr = t >> 4, tc = t & 15;
    const int lr = t >> 2;
    const int lc = (t & 3) << 2;

    // load Q tile transposed (q pre-scaled by 1/8)
    #pragma unroll
    for (int ii = 0; ii < 4; ++ii) {
        int dd = lc + ii * 16;
        float4 qv = *(const float4*)&q_ws[base + (size_t)(q0 + lr) * HD + dd];
        Qs[dd+0][lr] = qv.x; Qs[dd+1][lr] = qv.y; Qs[dd+2][lr] = qv.z; Qs[dd+3][lr] = qv.w;
    }
    if (t < 64) { mrow[t] = -INFINITY; lrow[t] = 0.0f; }
    float o[4][4] = {};
    __syncthreads();

    for (int kc0 = 0; kc0 < SEQ; kc0 += 64) {
        // --- load K tile transposed ---
        #pragma unroll
        for (int ii = 0; ii < 4; ++ii) {
            int dd = lc + ii * 16;
            float4 kv = *(const float4*)&k_ws[base + (size_t)(kc0 + lr) * HD + dd];
            KVs[dd+0][lr] = kv.x; KVs[dd+1][lr] = kv.y; KVs[dd+2][lr] = kv.z; KVs[dd+3][lr] = kv.w;
        }
        __syncthreads();

        // --- scores: s[qr][kc] = sum_d Qs[d][qr] * K[d][kc] ---
        float s[4][4] = {};
        #pragma unroll
        for (int d = 0; d < 64; ++d) {
            float4 qv = *(const float4*)&Qs[d][tr << 2];
            float4 kv = *(const float4*)&KVs[d][tc << 2];
            float qa[4] = {qv.x, qv.y, qv.z, qv.w};
            float ka[4] = {kv.x, kv.y, kv.z, kv.w};
            #pragma unroll
            for (int i = 0; i < 4; ++i)
                #pragma unroll
                for (int j = 0; j < 4; ++j)
                    s[i][j] = fmaf(qa[i], ka[j], s[i][j]);
        }

        // --- row-max partials ---
        #pragma unroll
        for (int i = 0; i < 4; ++i) {
            float rm = fmaxf(fmaxf(s[i][0], s[i][1]), fmaxf(s[i][2], s[i][3]));
            red[(tr << 2) + i][tc] = rm;
        }
        __syncthreads();
        if (t < 64) {
            float tm = red[t][0];
            #pragma unroll
            for (int j = 1; j < 16; ++j) tm = fmaxf(tm, red[t][j]);
            float mo = mrow[t];
            float mn = fmaxf(mo, tm);
            float f  = expf(mo - mn);      // 0 on first tile (mo = -inf)
            fbuf[t] = f;
            lrow[t] *= f;
            mrow[t] = mn;
        }
        __syncthreads();

        // --- rescale O, compute P, write Pt + row-sum partials ---
        float mloc[4], floc[4];
        #pragma unroll
        for (int i = 0; i < 4; ++i) {
            mloc[i] = mrow[(tr << 2) + i];
            floc[i] = fbuf[(tr << 2) + i];
        }
        #pragma unroll
        for (int i = 0; i < 4; ++i) {
            float rs = 0.0f;
            #pragma unroll
            for (int j = 0; j < 4; ++j) {
                o[i][j] *= floc[i];
                float p = expf(s[i][j] - mloc[i]);
                Pt[(tc << 2) + j][(tr << 2) + i] = p;
                rs += p;
            }
            red[(tr << 2) + i][tc] = rs;
        }
        // --- load V tile (natural layout) into same buffer ---
        #pragma unroll
        for (int ii = 0; ii < 4; ++ii) {
            int dd = lc + ii * 16;
            float4 vv = *(const float4*)&v_ws[base + (size_t)(kc0 + lr) * HD + dd];
            *(float4*)&KVs[lr][dd] = vv;
        }
        __syncthreads();
        if (t < 64) {
            float ts = 0.0f;
            #pragma unroll
            for (int j = 0; j < 16; ++j) ts += red[t][j];
            lrow[t] += ts;
        }

        // --- PV: o[qr][d] += sum_kc P[qr][kc] * V[kc][d] ---
        #pragma unroll
        for (int kc = 0; kc < 64; ++kc) {
            float4 pv = *(const float4*)&Pt[kc][tr << 2];
            float4 vv = *(const float4*)&KVs[kc][tc << 2];
            float pa[4] = {pv.x, pv.y, pv.z, pv.w};
            float va[4] = {vv.x, vv.y, vv.z, vv.w};
            #pragma unroll
            for (int i = 0; i < 4; ++i)
                #pragma unroll
                for (int j = 0; j < 4; ++j)
                    o[i][j] = fmaf(pa[i], va[j], o[i][j]);
        }
        __syncthreads();
    }

    // epilogue: normalize, write ctx as [b][s][h*64+d] so out-proj is a plain GEMM
    #pragma unroll
    for (int i = 0; i < 4; ++i) {
        int qr = (tr << 2) + i;
        float inv = 1.0f / lrow[qr];
        float4 r;
        r.x = o[i][0] * inv; r.y = o[i][1] * inv;
        r.z = o[i][2] * inv; r.w = o[i][3] * inv;
        size_t idx = ((size_t)(b * SEQ) + q0 + qr) * HIDDEN + h * HD + (tc << 2);
        *(float4*)&ctx[idx] = r;
    }
}

// ---------------------------------------------------------------------------
// Kernel 3: output projection. out[M=4096, 1024] = CTX * W_out^T + b_out
// ---------------------------------------------------------------------------
__global__ __launch_bounds__(256)
void out_proj(const float* __restrict__ CTX, const float* __restrict__ W,
              const float* __restrict__ bias, float* __restrict__ out)
{
    __shared__ float As[16][68];
    __shared__ float Bs[16][68];
    const int t  = threadIdx.x;
    const int m0 = blockIdx.x * 64;
    const int n0 = blockIdx.y * 64;
    const int tr = t >> 4, tc = t & 15;
    const int lr = t >> 2;
    const int lk = (t & 3) << 2;
    float acc[4][4] = {};

    const float* Arow = CTX + (size_t)(m0 + lr) * HIDDEN + lk;
    const float* Brow = W   + (size_t)(n0 + lr) * HIDDEN + lk;

    for (int k0 = 0; k0 < HIDDEN; k0 += 16) {
        float4 a = *(const float4*)(Arow + k0);
        float4 b = *(const float4*)(Brow + k0);
        __syncthreads();
        As[lk+0][lr] = a.x; As[lk+1][lr] = a.y; As[lk+2][lr] = a.z; As[lk+3][lr] = a.w;
        Bs[lk+0][lr] = b.x; Bs[lk+1][lr] = b.y; Bs[lk+2][lr] = b.z; Bs[lk+3][lr] = b.w;
        __syncthreads();
        #pragma unroll
        for (int k = 0; k < 16; ++k) {
            float4 av = *(const float4*)&As[k][tr << 2];
            float4 bv = *(const float4*)&Bs[k][tc << 2];
            float aa[4] = {av.x, av.y, av.z, av.w};
            float bb[4] = {bv.x, bv.y, bv.z, bv.w};
            #pragma unroll
            for (int i = 0; i < 4; ++i)
                #pragma unroll
                for (int j = 0; j < 4; ++j)
                    acc[i][j] = fmaf(aa[i], bb[j], acc[i][j]);
        }
    }

    const int o0 = n0 + (tc << 2);
    float4 bv = *(const float4*)&bias[o0];
    float bb[4] = {bv.x, bv.y, bv.z, bv.w};
    #pragma unroll
    for (int i = 0; i < 4; ++i) {
        int m = m0 + (tr << 2) + i;
        float4 r;
        r.x = acc[i][0] + bb[0];
        r.y = acc[i][1] + bb[1];
        r.z = acc[i][2] + bb[2];
        r.w = acc[i][3] + bb[3];
        *(float4*)&out[(size_t)m * HIDDEN + o0] = r;
    }
}

// ---------------------------------------------------------------------------
extern "C" void kernel_launch(void* const* d_in, const int* in_sizes, int n_in,
                              void* d_out, int out_size, void* d_ws, size_t ws_size,
                              hipStream_t stream)
{
    const float* x     = (const float*)d_in[0];
    const float* w_qkv = (const float*)d_in[1];
    const float* b_qkv = (const float*)d_in[2];
    const float* w_out = (const float*)d_in[3];
    const float* b_out = (const float*)d_in[4];
    float* out = (float*)d_out;
    float* ws  = (float*)d_ws;

    const size_t PH = (size_t)BATCH * HEADS * SEQ * HD;   // 4,194,304 floats
    float* q_ws = ws;
    float* k_ws = ws + PH;
    float* v_ws = ws + 2 * PH;
    float* ctxb = ws + 3 * PH;                            // [B*S][HIDDEN]

    qkv_proj<<<dim3(64, 48), 256, 0, stream>>>(x, w_qkv, b_qkv, q_ws, k_ws, v_ws);
    attn<<<dim3(SEQ / 64, HEADS, BATCH), 256, 0, stream>>>(q_ws, k_ws, v_ws, ctxb);
    out_proj<<<dim3(64, 16), 256, 0, stream>>>(ctxb, w_out, b_out, out);
}

// Round 2
// 606.533 us; speedup vs baseline: 1.6127x; 1.6127x over previous
//
#include <hip/hip_runtime.h>
#include <math.h>

#define BATCH 2
#define SEQ   2048
#define HIDDEN 1024
#define HEADS 16
#define HD    64
#define QSCALE 0.18033688011112042f   // log2(e)/8 : scores computed in exp2 domain

typedef __attribute__((ext_vector_type(8)))  short short8;
typedef __attribute__((ext_vector_type(16))) float f32x16;

__device__ __forceinline__ unsigned short f2bf(float f) {
    unsigned int u = __builtin_bit_cast(unsigned int, f);
    u = (u + 0x7FFFu + ((u >> 16) & 1u)) >> 16;   // round-to-nearest-even
    return (unsigned short)u;
}
__device__ __forceinline__ float bf2f(unsigned short h) {
    unsigned int u = ((unsigned int)h) << 16;
    return __builtin_bit_cast(float, u);
}
__device__ __forceinline__ void gl16(const void* g, void* l) {
    __builtin_amdgcn_global_load_lds(
        (const __attribute__((address_space(1))) void*)g,
        (__attribute__((address_space(3))) void*)l,
        16, 0, 0);
}

// ---------------------------------------------------------------------------
// Kernel 1: QKV projection (f32 GEMM, unchanged math). Epilogue emits
// split-bf16 planes: q_hi/lo, k_hi/lo as [b*h][s][d] (q pre-scaled by
// log2e/8); v transposed to vt_hi/lo [b*h][d][s].
// ---------------------------------------------------------------------------
__global__ __launch_bounds__(256)
void qkv_proj(const float* __restrict__ X, const float* __restrict__ W,
              const float* __restrict__ bias,
              unsigned short* __restrict__ q_hi, unsigned short* __restrict__ q_lo,
              unsigned short* __restrict__ k_hi, unsigned short* __restrict__ k_lo,
              unsigned short* __restrict__ vt_hi, unsigned short* __restrict__ vt_lo)
{
    __shared__ float As[16][68];   // [k][m]
    __shared__ float Bs[16][68];   // [k][n]
    const int t  = threadIdx.x;
    const int m0 = blockIdx.x * 64;
    const int n0 = blockIdx.y * 64;
    const int tr = t >> 4, tc = t & 15;
    const int lr = t >> 2;
    const int lk = (t & 3) << 2;
    float acc[4][4] = {};

    const float* Arow = X + (size_t)(m0 + lr) * HIDDEN + lk;
    const float* Brow = W + (size_t)(n0 + lr) * HIDDEN + lk;

    for (int k0 = 0; k0 < HIDDEN; k0 += 16) {
        float4 a = *(const float4*)(Arow + k0);
        float4 b = *(const float4*)(Brow + k0);
        __syncthreads();
        As[lk+0][lr] = a.x; As[lk+1][lr] = a.y; As[lk+2][lr] = a.z; As[lk+3][lr] = a.w;
        Bs[lk+0][lr] = b.x; Bs[lk+1][lr] = b.y; Bs[lk+2][lr] = b.z; Bs[lk+3][lr] = b.w;
        __syncthreads();
        #pragma unroll
        for (int k = 0; k < 16; ++k) {
            float4 av = *(const float4*)&As[k][tr << 2];
            float4 bv = *(const float4*)&Bs[k][tc << 2];
            float aa[4] = {av.x, av.y, av.z, av.w};
            float bb[4] = {bv.x, bv.y, bv.z, bv.w};
            #pragma unroll
            for (int i = 0; i < 4; ++i)
                #pragma unroll
                for (int j = 0; j < 4; ++j)
                    acc[i][j] = fmaf(aa[i], bb[j], acc[i][j]);
        }
    }

    const int o0    = n0 + (tc << 2);
    const int which = o0 >> 10;           // 0=q 1=k 2=v
    const int hh    = (o0 & 1023) >> 6;
    const int d0    = o0 & 63;
    float4 bv = *(const float4*)&bias[o0];
    float bb[4] = {bv.x, bv.y, bv.z, bv.w};
    const float scl = (which == 0) ? QSCALE : 1.0f;
    float r[4][4];
    #pragma unroll
    for (int i = 0; i < 4; ++i)
        #pragma unroll
        for (int j = 0; j < 4; ++j)
            r[i][j] = (acc[i][j] + bb[j]) * scl;

    const int b  = m0 >> 11;
    const int s0 = (m0 & 2047) + (tr << 2);

    if (which < 2) {
        unsigned short* ph = which ? k_hi : q_hi;
        unsigned short* pl = which ? k_lo : q_lo;
        #pragma unroll
        for (int i = 0; i < 4; ++i) {
            size_t idx = ((size_t)(b * HEADS + hh) * SEQ + (s0 + i)) * HD + d0;
            ushort4 h4, l4;
            h4.x = f2bf(r[i][0]); l4.x = f2bf(r[i][0] - bf2f(h4.x));
            h4.y = f2bf(r[i][1]); l4.y = f2bf(r[i][1] - bf2f(h4.y));
            h4.z = f2bf(r[i][2]); l4.z = f2bf(r[i][2] - bf2f(h4.z));
            h4.w = f2bf(r[i][3]); l4.w = f2bf(r[i][3] - bf2f(h4.w));
            *(ushort4*)&ph[idx] = h4;
            *(ushort4*)&pl[idx] = l4;
        }
    } else {
        #pragma unroll
        for (int j = 0; j < 4; ++j) {
            size_t idx = ((size_t)(b * HEADS + hh) * HD + (d0 + j)) * SEQ + s0;
            ushort4 h4, l4;
            h4.x = f2bf(r[0][j]); l4.x = f2bf(r[0][j] - bf2f(h4.x));
            h4.y = f2bf(r[1][j]); l4.y = f2bf(r[1][j] - bf2f(h4.y));
            h4.z = f2bf(r[2][j]); l4.z = f2bf(r[2][j] - bf2f(h4.z));
            h4.w = f2bf(r[3][j]); l4.w = f2bf(r[3][j] - bf2f(h4.w));
            *(ushort4*)&vt_hi[idx] = h4;
            *(ushort4*)&vt_lo[idx] = l4;
        }
    }
}

// ---------------------------------------------------------------------------
// Kernel 2: MFMA flash attention, split-bf16 (3-term), swapped operands.
// Block = 256 thr (4 waves), Q-tile 128 (32 q/wave), K-tile 32.
// S^T = mfma(K, Q) -> lane owns q-col (l&31): lane-local online softmax.
// P stays in registers; PV B-operand built via shfl_xor(32) word exchange.
// ctx^T accumulated in regs; epilogue transposes via swizzled LDS -> f32 ctx.
// ---------------------------------------------------------------------------
#define NKT (SEQ / 32)

__global__ __launch_bounds__(256)
void attn_mfma(const unsigned short* __restrict__ q_hi, const unsigned short* __restrict__ q_lo,
               const unsigned short* __restrict__ k_hi, const unsigned short* __restrict__ k_lo,
               const unsigned short* __restrict__ vt_hi, const unsigned short* __restrict__ vt_lo,
               float* __restrict__ ctx)
{
    __shared__ char smem[65536];
    const int t    = threadIdx.x;
    const int lane = t & 63;
    const int wq   = t >> 6;          // wave id = q-quarter
    const int l31  = lane & 31;
    const int hh   = lane >> 5;
    const int q0   = blockIdx.x * 128;
    const size_t bh = (size_t)(blockIdx.z * HEADS + blockIdx.y);

    const char* qhB = (const char*)(q_hi + bh * SEQ * HD);
    const char* qlB = (const char*)(q_lo + bh * SEQ * HD);
    const char* khB = (const char*)(k_hi + bh * SEQ * HD);
    const char* klB = (const char*)(k_lo + bh * SEQ * HD);
    const char* vhB = (const char*)(vt_hi + bh * SEQ * HD);
    const char* vlB = (const char*)(vt_lo + bh * SEQ * HD);

    // LDS map: [0,16K) Q_hi, [16K,32K) Q_lo (reused as ctx transpose buffer),
    // [32K + buf*8K + pl*4K) K tiles, [48K + buf*8K + pl*4K) VT tiles.
    const int QHI = 0, QLO = 16384, KB = 32768, VB = 49152;
    const int wbase = wq * 1024;      // per-wave linear staging base

    // ---- prologue staging: Q (4 issues/plane), K/VT tile 0 ----
    {
        int rr = t >> 3, cc = t & 7;
        #pragma unroll
        for (int i = 0; i < 4; ++i) {
            int row = i * 32 + rr;
            int ch  = cc ^ (row & 7);
            gl16(qhB + (size_t)(q0 + row) * 128 + ch * 16, smem + QHI + i * 4096 + wbase);
            gl16(qlB + (size_t)(q0 + row) * 128 + ch * 16, smem + QLO + i * 4096 + wbase);
        }
    }
    auto stageK = [&](int buf, int kt) {
        int rr = t >> 3;
        int ch = (t & 7) ^ (rr & 7);
        size_t goff = (size_t)(kt * 32 + rr) * 128 + ch * 16;
        gl16(khB + goff, smem + KB + buf * 8192 +    0 + wbase);
        gl16(klB + goff, smem + KB + buf * 8192 + 4096 + wbase);
    };
    auto stageV = [&](int buf, int kt) {
        int rr = t >> 2;
        int s4 = (rr & 3) ^ ((rr >> 2) & 3);
        int ch = (t & 3) ^ s4;
        size_t goff = (size_t)rr * (SEQ * 2) + (size_t)kt * 64 + ch * 16;
        gl16(vhB + goff, smem + VB + buf * 8192 +    0 + wbase);
        gl16(vlB + goff, smem + VB + buf * 8192 + 4096 + wbase);
    };
    stageK(0, 0);
    stageV(0, 0);
    __syncthreads();

    // ---- hoist Q fragments (B-operand) to registers ----
    short8 qfh[4], qfl[4];
    {
        int qrow = 32 * wq + l31;
        #pragma unroll
        for (int ks = 0; ks < 4; ++ks) {
            int ch = ((2 * ks + hh) ^ (qrow & 7)) * 16;
            qfh[ks] = *(const short8*)(smem + QHI + qrow * 128 + ch);
            qfl[ks] = *(const short8*)(smem + QLO + qrow * 128 + ch);
        }
    }

    f32x16 acc0 = {}, acc1 = {};
    float m = -1e30f, lsum = 0.0f;
    int cur = 0;

    for (int kt = 0; kt < NKT; ++kt) {
        if (kt + 1 < NKT) { stageK(cur ^ 1, kt + 1); stageV(cur ^ 1, kt + 1); }

        // --- S^T = K . Q^T  (3-term split) ---
        f32x16 sacc = {};
        const char* Kh = smem + KB + cur * 8192;
        const char* Kl = Kh + 4096;
        #pragma unroll
        for (int ks = 0; ks < 4; ++ks) {
            int ch = ((2 * ks + hh) ^ (l31 & 7)) * 16;
            short8 a_h = *(const short8*)(Kh + l31 * 128 + ch);
            short8 a_l = *(const short8*)(Kl + l31 * 128 + ch);
            sacc = __builtin_amdgcn_mfma_f32_32x32x16_bf16(a_h, qfh[ks], sacc, 0, 0, 0);
            sacc = __builtin_amdgcn_mfma_f32_32x32x16_bf16(a_h, qfl[ks], sacc, 0, 0, 0);
            sacc = __builtin_amdgcn_mfma_f32_32x32x16_bf16(a_l, qfh[ks], sacc, 0, 0, 0);
        }

        // --- online softmax, lane-local (q = l31), partner = lane^32 ---
        float pmax = sacc[0];
        #pragma unroll
        for (int i = 1; i < 16; ++i) pmax = fmaxf(pmax, sacc[i]);
        pmax = fmaxf(pmax, __shfl_xor(pmax, 32, 64));
        if (!__all(pmax - m <= 8.0f)) {        // defer-max (exp2 domain, THR=8)
            float mn = fmaxf(m, pmax);
            float f  = exp2f(m - mn);
            lsum *= f;
            #pragma unroll
            for (int i = 0; i < 16; ++i) { acc0[i] *= f; acc1[i] *= f; }
            m = mn;
        }
        unsigned int phi[8], plo[8];
        float psum = 0.0f;
        #pragma unroll
        for (int w = 0; w < 8; ++w) {
            float p0 = exp2f(sacc[2 * w]     - m);
            float p1 = exp2f(sacc[2 * w + 1] - m);
            psum += p0 + p1;
            unsigned short b0 = f2bf(p0), b1 = f2bf(p1);
            phi[w] = (unsigned int)b0 | ((unsigned int)b1 << 16);
            unsigned short c0 = f2bf(p0 - bf2f(b0)), c1 = f2bf(p1 - bf2f(b1));
            plo[w] = (unsigned int)c0 | ((unsigned int)c1 << 16);
        }
        psum += __shfl_xor(psum, 32, 64);
        lsum += psum;

        unsigned int rhi[8], rlo[8];
        #pragma unroll
        for (int w = 0; w < 8; ++w) {
            rhi[w] = __shfl_xor(phi[w], 32, 64);
            rlo[w] = __shfl_xor(plo[w], 32, 64);
        }

        // --- ctx^T += V^T . P^T  (3-term split) ---
        const char* Vh = smem + VB + cur * 8192;
        const char* Vl = Vh + 4096;
        #pragma unroll
        for (int ks = 0; ks < 2; ++ks) {
            uint4 uh, ul;
            if (hh == 0) {
                uh = make_uint4(phi[4*ks], phi[4*ks+1], rhi[4*ks], rhi[4*ks+1]);
                ul = make_uint4(plo[4*ks], plo[4*ks+1], rlo[4*ks], rlo[4*ks+1]);
            } else {
                uh = make_uint4(rhi[4*ks+2], rhi[4*ks+3], phi[4*ks+2], phi[4*ks+3]);
                ul = make_uint4(rlo[4*ks+2], rlo[4*ks+3], plo[4*ks+2], plo[4*ks+3]);
            }
            short8 pF = __builtin_bit_cast(short8, uh);
            short8 pL = __builtin_bit_cast(short8, ul);
            #pragma unroll
            for (int mt = 0; mt < 2; ++mt) {
                int rrow = 32 * mt + l31;
                int s4   = (rrow & 3) ^ ((rrow >> 2) & 3);
                int ch   = ((2 * ks + hh) ^ s4) * 16;
                short8 v_h = *(const short8*)(Vh + rrow * 64 + ch);
                short8 v_l = *(const short8*)(Vl + rrow * 64 + ch);
                if (mt == 0) {
                    acc0 = __builtin_amdgcn_mfma_f32_32x32x16_bf16(v_h, pF, acc0, 0, 0, 0);
                    acc0 = __builtin_amdgcn_mfma_f32_32x32x16_bf16(v_h, pL, acc0, 0, 0, 0);
                    acc0 = __builtin_amdgcn_mfma_f32_32x32x16_bf16(v_l, pF, acc0, 0, 0, 0);
                } else {
                    acc1 = __builtin_amdgcn_mfma_f32_32x32x16_bf16(v_h, pF, acc1, 0, 0, 0);
                    acc1 = __builtin_amdgcn_mfma_f32_32x32x16_bf16(v_h, pL, acc1, 0, 0, 0);
                    acc1 = __builtin_amdgcn_mfma_f32_32x32x16_bf16(v_l, pF, acc1, 0, 0, 0);
                }
            }
        }
        __syncthreads();
        cur ^= 1;
    }

    // ---- epilogue: normalize, transpose via swizzled LDS, store f32 ctx ----
    float inv = 1.0f / lsum;
    {
        int q = 32 * wq + l31;
        #pragma unroll
        for (int mt = 0; mt < 2; ++mt) {
            #pragma unroll
            for (int m2 = 0; m2 < 4; ++m2) {
                float4 v4;
                if (mt == 0) {
                    v4.x = acc0[4*m2+0] * inv; v4.y = acc0[4*m2+1] * inv;
                    v4.z = acc0[4*m2+2] * inv; v4.w = acc0[4*m2+3] * inv;
                } else {
                    v4.x = acc1[4*m2+0] * inv; v4.y = acc1[4*m2+1] * inv;
                    v4.z = acc1[4*m2+2] * inv; v4.w = acc1[4*m2+3] * inv;
                }
                int d0 = 4 * hh + 8 * m2 + 32 * mt;
                int ch = (d0 >> 2) ^ (q & 15);
                *(float4*)(smem + q * 256 + ch * 16) = v4;
            }
        }
    }
    __syncthreads();
    {
        const int cl = t >> 4, ln = t & 15;
        #pragma unroll
        for (int rr = 0; rr < 8; ++rr) {
            int row = cl * 8 + rr;
            int ch  = ln ^ (row & 15);
            float4 v4 = *(const float4*)(smem + row * 256 + ch * 16);
            *(float4*)&ctx[((size_t)(blockIdx.z * SEQ) + q0 + row) * HIDDEN
                           + blockIdx.y * HD + 4 * ln] = v4;
        }
    }
}

// ---------------------------------------------------------------------------
// Kernel 3: output projection (f32, unchanged).
// ---------------------------------------------------------------------------
__global__ __launch_bounds__(256)
void out_proj(const float* __restrict__ CTX, const float* __restrict__ W,
              const float* __restrict__ bias, float* __restrict__ out)
{
    __shared__ float As[16][68];
    __shared__ float Bs[16][68];
    const int t  = threadIdx.x;
    const int m0 = blockIdx.x * 64;
    const int n0 = blockIdx.y * 64;
    const int tr = t >> 4, tc = t & 15;
    const int lr = t >> 2;
    const int lk = (t & 3) << 2;
    float acc[4][4] = {};

    const float* Arow = CTX + (size_t)(m0 + lr) * HIDDEN + lk;
    const float* Brow = W   + (size_t)(n0 + lr) * HIDDEN + lk;

    for (int k0 = 0; k0 < HIDDEN; k0 += 16) {
        float4 a = *(const float4*)(Arow + k0);
        float4 b = *(const float4*)(Brow + k0);
        __syncthreads();
        As[lk+0][lr] = a.x; As[lk+1][lr] = a.y; As[lk+2][lr] = a.z; As[lk+3][lr] = a.w;
        Bs[lk+0][lr] = b.x; Bs[lk+1][lr] = b.y; Bs[lk+2][lr] = b.z; Bs[lk+3][lr] = b.w;
        __syncthreads();
        #pragma unroll
        for (int k = 0; k < 16; ++k) {
            float4 av = *(const float4*)&As[k][tr << 2];
            float4 bv = *(const float4*)&Bs[k][tc << 2];
            float aa[4] = {av.x, av.y, av.z, av.w};
            float bb[4] = {bv.x, bv.y, bv.z, bv.w};
            #pragma unroll
            for (int i = 0; i < 4; ++i)
                #pragma unroll
                for (int j = 0; j < 4; ++j)
                    acc[i][j] = fmaf(aa[i], bb[j], acc[i][j]);
        }
    }

    const int o0 = n0 + (tc << 2);
    float4 bv = *(const float4*)&bias[o0];
    float bb[4] = {bv.x, bv.y, bv.z, bv.w};
    #pragma unroll
    for (int i = 0; i < 4; ++i) {
        int mm = m0 + (tr << 2) + i;
        float4 r;
        r.x = acc[i][0] + bb[0];
        r.y = acc[i][1] + bb[1];
        r.z = acc[i][2] + bb[2];
        r.w = acc[i][3] + bb[3];
        *(float4*)&out[(size_t)mm * HIDDEN + o0] = r;
    }
}

// ---------------------------------------------------------------------------
extern "C" void kernel_launch(void* const* d_in, const int* in_sizes, int n_in,
                              void* d_out, int out_size, void* d_ws, size_t ws_size,
                              hipStream_t stream)
{
    const float* x     = (const float*)d_in[0];
    const float* w_qkv = (const float*)d_in[1];
    const float* b_qkv = (const float*)d_in[2];
    const float* w_out = (const float*)d_in[3];
    const float* b_out = (const float*)d_in[4];
    float* out = (float*)d_out;

    const size_t PH = (size_t)BATCH * HEADS * SEQ * HD;   // 4,194,304 elems/plane
    unsigned short* q_hi  = (unsigned short*)d_ws;
    unsigned short* q_lo  = q_hi + PH;
    unsigned short* k_hi  = q_hi + 2 * PH;
    unsigned short* k_lo  = q_hi + 3 * PH;
    unsigned short* vt_hi = q_hi + 4 * PH;
    unsigned short* vt_lo = q_hi + 5 * PH;
    float* ctxb = (float*)(q_hi + 6 * PH);                // [B*S][HIDDEN] f32

    qkv_proj<<<dim3(64, 48), 256, 0, stream>>>(x, w_qkv, b_qkv,
                                               q_hi, q_lo, k_hi, k_lo, vt_hi, vt_lo);
    attn_mfma<<<dim3(SEQ / 128, HEADS, BATCH), 256, 0, stream>>>(
        q_hi, q_lo, k_hi, k_lo, vt_hi, vt_lo, ctxb);
    out_proj<<<dim3(64, 16), 256, 0, stream>>>(ctxb, w_out, b_out, out);
}

// Round 3
// 280.147 us; speedup vs baseline: 3.4915x; 2.1651x over previous
//
#include <hip/hip_runtime.h>
#include <math.h>

#define BATCH 2
#define SEQ   2048
#define HIDDEN 1024
#define HEADS 16
#define HD    64
#define QSCALE 0.18033688011112042f   // log2(e)/8 : scores computed in exp2 domain

typedef __attribute__((ext_vector_type(8)))  short short8;
typedef __attribute__((ext_vector_type(16))) float f32x16;

__device__ __forceinline__ unsigned short f2bf(float f) {
    unsigned int u = __builtin_bit_cast(unsigned int, f);
    u = (u + 0x7FFFu + ((u >> 16) & 1u)) >> 16;   // round-to-nearest-even
    return (unsigned short)u;
}
__device__ __forceinline__ float bf2f(unsigned short h) {
    unsigned int u = ((unsigned int)h) << 16;
    return __builtin_bit_cast(float, u);
}
__device__ __forceinline__ void gl16(const void* g, void* l) {
    __builtin_amdgcn_global_load_lds(
        (const __attribute__((address_space(1))) void*)g,
        (__attribute__((address_space(3))) void*)l,
        16, 0, 0);
}

// ---------------------------------------------------------------------------
// conv_split: f32 -> (hi, lo) bf16 planes. Grid sized exactly (n/4 /256).
// ---------------------------------------------------------------------------
__global__ __launch_bounds__(256)
void conv_split(const float* __restrict__ src,
                unsigned short* __restrict__ hi, unsigned short* __restrict__ lo)
{
    int idx = blockIdx.x * 256 + threadIdx.x;
    float4 v = ((const float4*)src)[idx];
    ushort4 h4, l4;
    h4.x = f2bf(v.x); l4.x = f2bf(v.x - bf2f(h4.x));
    h4.y = f2bf(v.y); l4.y = f2bf(v.y - bf2f(h4.y));
    h4.z = f2bf(v.z); l4.z = f2bf(v.z - bf2f(h4.z));
    h4.w = f2bf(v.w); l4.w = f2bf(v.w - bf2f(h4.w));
    ((ushort4*)hi)[idx] = h4;
    ((ushort4*)lo)[idx] = l4;
}

// ---------------------------------------------------------------------------
// Split-bf16 MFMA GEMM core: C[128x128] += A[128xK] * B[128xK]^T (3-term).
// A,B planes row-major stride 1024 elems. BK=32, interleaved hi/lo in
// 128B LDS rows, chunk-XOR swizzle (rule #21: pre-swizzled global source,
// linear global_load_lds dest, swizzled ds_read). Double-buffered, 64KB LDS.
// Accumulators: 2x2 frags of 32x32 per wave (2x2 wave grid).
// ---------------------------------------------------------------------------
__device__ __forceinline__ void gemm_core(
    const char* Ah, const char* Al, const char* Bh, const char* Bl,
    int m0, int n0, char* smem, f32x16 acc[2][2])
{
    const int t    = threadIdx.x;
    const int lane = t & 63;
    const int w    = t >> 6;
    const int wm   = w >> 1, wn = w & 1;
    const int l31  = lane & 31, hh = lane >> 5;
    const int srow = lane >> 3;
    const int sc   = lane & 7;

    auto stage = [&](int buf, int kt) {
        #pragma unroll
        for (int i = 0; i < 4; ++i) {
            int r = i * 32 + w * 8 + srow;
            int c = sc ^ (r & 7);                    // chunk: 0-3 hi, 4-7 lo
            size_t go = ((size_t)(m0 + r) * 1024 + kt * 32 + (c & 3) * 8) * 2;
            gl16(((c & 4) ? Al : Ah) + go, smem + buf * 32768 + i * 4096 + w * 1024);
            size_t gob = ((size_t)(n0 + r) * 1024 + kt * 32 + (c & 3) * 8) * 2;
            gl16(((c & 4) ? Bl : Bh) + gob, smem + buf * 32768 + 16384 + i * 4096 + w * 1024);
        }
    };

    stage(0, 0);
    __syncthreads();

    for (int kt = 0; kt < 32; ++kt) {
        if (kt + 1 < 32) stage((kt & 1) ^ 1, kt + 1);
        const char* Ab = smem + (kt & 1) * 32768;
        const char* Bb = Ab + 16384;
        #pragma unroll
        for (int ks = 0; ks < 2; ++ks) {
            short8 ah[2], al[2], bh[2], bl[2];
            #pragma unroll
            for (int mt = 0; mt < 2; ++mt) {
                int R  = wm * 64 + mt * 32 + l31;
                int ch = ((ks * 2 + hh) ^ (R & 7)) * 16;
                int cl = ((4 + ks * 2 + hh) ^ (R & 7)) * 16;
                ah[mt] = *(const short8*)(Ab + R * 128 + ch);
                al[mt] = *(const short8*)(Ab + R * 128 + cl);
            }
            #pragma unroll
            for (int nt = 0; nt < 2; ++nt) {
                int R  = wn * 64 + nt * 32 + l31;
                int ch = ((ks * 2 + hh) ^ (R & 7)) * 16;
                int cl = ((4 + ks * 2 + hh) ^ (R & 7)) * 16;
                bh[nt] = *(const short8*)(Bb + R * 128 + ch);
                bl[nt] = *(const short8*)(Bb + R * 128 + cl);
            }
            #pragma unroll
            for (int mt = 0; mt < 2; ++mt)
                #pragma unroll
                for (int nt = 0; nt < 2; ++nt) {
                    acc[mt][nt] = __builtin_amdgcn_mfma_f32_32x32x16_bf16(ah[mt], bh[nt], acc[mt][nt], 0, 0, 0);
                    acc[mt][nt] = __builtin_amdgcn_mfma_f32_32x32x16_bf16(ah[mt], bl[nt], acc[mt][nt], 0, 0, 0);
                    acc[mt][nt] = __builtin_amdgcn_mfma_f32_32x32x16_bf16(al[mt], bh[nt], acc[mt][nt], 0, 0, 0);
                }
        }
        __syncthreads();
    }
}

// ---------------------------------------------------------------------------
// Kernel: QKV GEMM + scatter epilogue (bias, q-scale, split-bf16 planes,
// V transposed). Repack goes through a full-block 128x128 f32 LDS tile.
// ---------------------------------------------------------------------------
__global__ __launch_bounds__(256, 2)
void qkv_gemm(const unsigned short* __restrict__ xh, const unsigned short* __restrict__ xl,
              const unsigned short* __restrict__ wh, const unsigned short* __restrict__ wl,
              const float* __restrict__ bias,
              unsigned short* __restrict__ q_hi, unsigned short* __restrict__ q_lo,
              unsigned short* __restrict__ k_hi, unsigned short* __restrict__ k_lo,
              unsigned short* __restrict__ vt_hi, unsigned short* __restrict__ vt_lo)
{
    __shared__ char smem[65536];
    f32x16 acc[2][2] = {{{}, {}}, {{}, {}}};
    const int m0 = blockIdx.x * 128, n0 = blockIdx.y * 128;
    gemm_core((const char*)xh, (const char*)xl, (const char*)wh, (const char*)wl,
              m0, n0, smem, acc);

    const int t    = threadIdx.x;
    const int lane = t & 63;
    const int w    = t >> 6;
    const int wm   = w >> 1, wn = w & 1;
    const int l31  = lane & 31, hh = lane >> 5;

    // stash acc into LDS [128][128] f32 (row = 512B)
    #pragma unroll
    for (int mt = 0; mt < 2; ++mt)
        #pragma unroll
        for (int nt = 0; nt < 2; ++nt) {
            int nl = wn * 64 + nt * 32 + l31;
            #pragma unroll
            for (int r = 0; r < 16; ++r) {
                int ml = wm * 64 + mt * 32 + (r & 3) + 8 * (r >> 2) + 4 * hh;
                *(float*)(smem + ml * 512 + nl * 4) = acc[mt][nt][r];
            }
        }
    __syncthreads();

    const int which = n0 >> 10;            // 0=q 1=k 2=v (tiles never straddle)
    const int hbase = (n0 & 1023) >> 6;
    const int b     = m0 >> 11;
    const int s0    = m0 & 2047;

    if (which < 2) {
        unsigned short* ph = which ? k_hi : q_hi;
        unsigned short* pl = which ? k_lo : q_lo;
        const float scl = (which == 0) ? QSCALE : 1.0f;
        const int nc = t & 31;
        float4 b4 = *(const float4*)&bias[n0 + nc * 4];
        const int head = hbase + (nc >> 4);
        const int d0   = (nc & 15) * 4;
        #pragma unroll
        for (int it = 0; it < 16; ++it) {
            int m = it * 8 + (t >> 5);
            float4 v = *(const float4*)(smem + m * 512 + nc * 16);
            float r0 = (v.x + b4.x) * scl, r1 = (v.y + b4.y) * scl;
            float r2 = (v.z + b4.z) * scl, r3 = (v.w + b4.w) * scl;
            ushort4 h4, l4;
            h4.x = f2bf(r0); l4.x = f2bf(r0 - bf2f(h4.x));
            h4.y = f2bf(r1); l4.y = f2bf(r1 - bf2f(h4.y));
            h4.z = f2bf(r2); l4.z = f2bf(r2 - bf2f(h4.z));
            h4.w = f2bf(r3); l4.w = f2bf(r3 - bf2f(h4.w));
            size_t idx = (((size_t)(b * HEADS + head)) * SEQ + s0 + m) * HD + d0;
            *(ushort4*)&ph[idx] = h4;
            *(ushort4*)&pl[idx] = l4;
        }
    } else {
        const int nl   = t & 127;
        const float bs = bias[n0 + nl];
        const int head = hbase + (nl >> 6);
        const int d    = nl & 63;
        #pragma unroll
        for (int it = 0; it < 16; ++it) {
            int mq = it * 2 + (t >> 7);    // 0..31
            float r0 = *(const float*)(smem + (mq * 4 + 0) * 512 + nl * 4) + bs;
            float r1 = *(const float*)(smem + (mq * 4 + 1) * 512 + nl * 4) + bs;
            float r2 = *(const float*)(smem + (mq * 4 + 2) * 512 + nl * 4) + bs;
            float r3 = *(const float*)(smem + (mq * 4 + 3) * 512 + nl * 4) + bs;
            ushort4 h4, l4;
            h4.x = f2bf(r0); l4.x = f2bf(r0 - bf2f(h4.x));
            h4.y = f2bf(r1); l4.y = f2bf(r1 - bf2f(h4.y));
            h4.z = f2bf(r2); l4.z = f2bf(r2 - bf2f(h4.z));
            h4.w = f2bf(r3); l4.w = f2bf(r3 - bf2f(h4.w));
            size_t idx = (((size_t)(b * HEADS + head)) * HD + d) * SEQ + s0 + mq * 4;
            *(ushort4*)&vt_hi[idx] = h4;
            *(ushort4*)&vt_lo[idx] = l4;
        }
    }
}

// ---------------------------------------------------------------------------
// Kernel: output projection GEMM (split-bf16 MFMA), direct f32 epilogue.
// ---------------------------------------------------------------------------
__global__ __launch_bounds__(256, 2)
void out_gemm(const unsigned short* __restrict__ ah_, const unsigned short* __restrict__ al_,
              const unsigned short* __restrict__ bh_, const unsigned short* __restrict__ bl_,
              const float* __restrict__ bias, float* __restrict__ out)
{
    __shared__ char smem[65536];
    f32x16 acc[2][2] = {{{}, {}}, {{}, {}}};
    const int m0 = blockIdx.x * 128, n0 = blockIdx.y * 128;
    gemm_core((const char*)ah_, (const char*)al_, (const char*)bh_, (const char*)bl_,
              m0, n0, smem, acc);

    const int t    = threadIdx.x;
    const int lane = t & 63;
    const int w    = t >> 6;
    const int wm   = w >> 1, wn = w & 1;
    const int l31  = lane & 31, hh = lane >> 5;

    #pragma unroll
    for (int mt = 0; mt < 2; ++mt)
        #pragma unroll
        for (int nt = 0; nt < 2; ++nt) {
            int n = n0 + wn * 64 + nt * 32 + l31;
            float bb = bias[n];
            #pragma unroll
            for (int r = 0; r < 16; ++r) {
                int m = m0 + wm * 64 + mt * 32 + (r & 3) + 8 * (r >> 2) + 4 * hh;
                out[(size_t)m * 1024 + n] = acc[mt][nt][r] + bb;
            }
        }
}

// ---------------------------------------------------------------------------
// Kernel: MFMA flash attention (unchanged from round 2).
// ---------------------------------------------------------------------------
#define NKT (SEQ / 32)

__global__ __launch_bounds__(256)
void attn_mfma(const unsigned short* __restrict__ q_hi, const unsigned short* __restrict__ q_lo,
               const unsigned short* __restrict__ k_hi, const unsigned short* __restrict__ k_lo,
               const unsigned short* __restrict__ vt_hi, const unsigned short* __restrict__ vt_lo,
               float* __restrict__ ctx)
{
    __shared__ char smem[65536];
    const int t    = threadIdx.x;
    const int lane = t & 63;
    const int wq   = t >> 6;
    const int l31  = lane & 31;
    const int hh   = lane >> 5;
    const int q0   = blockIdx.x * 128;
    const size_t bh = (size_t)(blockIdx.z * HEADS + blockIdx.y);

    const char* qhB = (const char*)(q_hi + bh * SEQ * HD);
    const char* qlB = (const char*)(q_lo + bh * SEQ * HD);
    const char* khB = (const char*)(k_hi + bh * SEQ * HD);
    const char* klB = (const char*)(k_lo + bh * SEQ * HD);
    const char* vhB = (const char*)(vt_hi + bh * SEQ * HD);
    const char* vlB = (const char*)(vt_lo + bh * SEQ * HD);

    const int QHI = 0, QLO = 16384, KB = 32768, VB = 49152;
    const int wbase = wq * 1024;

    {
        int rr = t >> 3, cc = t & 7;
        #pragma unroll
        for (int i = 0; i < 4; ++i) {
            int row = i * 32 + rr;
            int ch  = cc ^ (row & 7);
            gl16(qhB + (size_t)(q0 + row) * 128 + ch * 16, smem + QHI + i * 4096 + wbase);
            gl16(qlB + (size_t)(q0 + row) * 128 + ch * 16, smem + QLO + i * 4096 + wbase);
        }
    }
    auto stageK = [&](int buf, int kt) {
        int rr = t >> 3;
        int ch = (t & 7) ^ (rr & 7);
        size_t goff = (size_t)(kt * 32 + rr) * 128 + ch * 16;
        gl16(khB + goff, smem + KB + buf * 8192 +    0 + wbase);
        gl16(klB + goff, smem + KB + buf * 8192 + 4096 + wbase);
    };
    auto stageV = [&](int buf, int kt) {
        int rr = t >> 2;
        int s4 = (rr & 3) ^ ((rr >> 2) & 3);
        int ch = (t & 3) ^ s4;
        size_t goff = (size_t)rr * (SEQ * 2) + (size_t)kt * 64 + ch * 16;
        gl16(vhB + goff, smem + VB + buf * 8192 +    0 + wbase);
        gl16(vlB + goff, smem + VB + buf * 8192 + 4096 + wbase);
    };
    stageK(0, 0);
    stageV(0, 0);
    __syncthreads();

    short8 qfh[4], qfl[4];
    {
        int qrow = 32 * wq + l31;
        #pragma unroll
        for (int ks = 0; ks < 4; ++ks) {
            int ch = ((2 * ks + hh) ^ (qrow & 7)) * 16;
            qfh[ks] = *(const short8*)(smem + QHI + qrow * 128 + ch);
            qfl[ks] = *(const short8*)(smem + QLO + qrow * 128 + ch);
        }
    }

    f32x16 acc0 = {}, acc1 = {};
    float m = -1e30f, lsum = 0.0f;
    int cur = 0;

    for (int kt = 0; kt < NKT; ++kt) {
        if (kt + 1 < NKT) { stageK(cur ^ 1, kt + 1); stageV(cur ^ 1, kt + 1); }

        f32x16 sacc = {};
        const char* Kh = smem + KB + cur * 8192;
        const char* Kl = Kh + 4096;
        #pragma unroll
        for (int ks = 0; ks < 4; ++ks) {
            int ch = ((2 * ks + hh) ^ (l31 & 7)) * 16;
            short8 a_h = *(const short8*)(Kh + l31 * 128 + ch);
            short8 a_l = *(const short8*)(Kl + l31 * 128 + ch);
            sacc = __builtin_amdgcn_mfma_f32_32x32x16_bf16(a_h, qfh[ks], sacc, 0, 0, 0);
            sacc = __builtin_amdgcn_mfma_f32_32x32x16_bf16(a_h, qfl[ks], sacc, 0, 0, 0);
            sacc = __builtin_amdgcn_mfma_f32_32x32x16_bf16(a_l, qfh[ks], sacc, 0, 0, 0);
        }

        float pmax = sacc[0];
        #pragma unroll
        for (int i = 1; i < 16; ++i) pmax = fmaxf(pmax, sacc[i]);
        pmax = fmaxf(pmax, __shfl_xor(pmax, 32, 64));
        if (!__all(pmax - m <= 8.0f)) {
            float mn = fmaxf(m, pmax);
            float f  = exp2f(m - mn);
            lsum *= f;
            #pragma unroll
            for (int i = 0; i < 16; ++i) { acc0[i] *= f; acc1[i] *= f; }
            m = mn;
        }
        unsigned int phi[8], plo[8];
        float psum = 0.0f;
        #pragma unroll
        for (int w = 0; w < 8; ++w) {
            float p0 = exp2f(sacc[2 * w]     - m);
            float p1 = exp2f(sacc[2 * w + 1] - m);
            psum += p0 + p1;
            unsigned short b0 = f2bf(p0), b1 = f2bf(p1);
            phi[w] = (unsigned int)b0 | ((unsigned int)b1 << 16);
            unsigned short c0 = f2bf(p0 - bf2f(b0)), c1 = f2bf(p1 - bf2f(b1));
            plo[w] = (unsigned int)c0 | ((unsigned int)c1 << 16);
        }
        psum += __shfl_xor(psum, 32, 64);
        lsum += psum;

        unsigned int rhi[8], rlo[8];
        #pragma unroll
        for (int w = 0; w < 8; ++w) {
            rhi[w] = __shfl_xor(phi[w], 32, 64);
            rlo[w] = __shfl_xor(plo[w], 32, 64);
        }

        const char* Vh = smem + VB + cur * 8192;
        const char* Vl = Vh + 4096;
        #pragma unroll
        for (int ks = 0; ks < 2; ++ks) {
            uint4 uh, ul;
            if (hh == 0) {
                uh = make_uint4(phi[4*ks], phi[4*ks+1], rhi[4*ks], rhi[4*ks+1]);
                ul = make_uint4(plo[4*ks], plo[4*ks+1], rlo[4*ks], rlo[4*ks+1]);
            } else {
                uh = make_uint4(rhi[4*ks+2], rhi[4*ks+3], phi[4*ks+2], phi[4*ks+3]);
                ul = make_uint4(rlo[4*ks+2], rlo[4*ks+3], plo[4*ks+2], plo[4*ks+3]);
            }
            short8 pF = __builtin_bit_cast(short8, uh);
            short8 pL = __builtin_bit_cast(short8, ul);
            #pragma unroll
            for (int mt = 0; mt < 2; ++mt) {
                int rrow = 32 * mt + l31;
                int s4   = (rrow & 3) ^ ((rrow >> 2) & 3);
                int ch   = ((2 * ks + hh) ^ s4) * 16;
                short8 v_h = *(const short8*)(Vh + rrow * 64 + ch);
                short8 v_l = *(const short8*)(Vl + rrow * 64 + ch);
                if (mt == 0) {
                    acc0 = __builtin_amdgcn_mfma_f32_32x32x16_bf16(v_h, pF, acc0, 0, 0, 0);
                    acc0 = __builtin_amdgcn_mfma_f32_32x32x16_bf16(v_h, pL, acc0, 0, 0, 0);
                    acc0 = __builtin_amdgcn_mfma_f32_32x32x16_bf16(v_l, pF, acc0, 0, 0, 0);
                } else {
                    acc1 = __builtin_amdgcn_mfma_f32_32x32x16_bf16(v_h, pF, acc1, 0, 0, 0);
                    acc1 = __builtin_amdgcn_mfma_f32_32x32x16_bf16(v_h, pL, acc1, 0, 0, 0);
                    acc1 = __builtin_amdgcn_mfma_f32_32x32x16_bf16(v_l, pF, acc1, 0, 0, 0);
                }
            }
        }
        __syncthreads();
        cur ^= 1;
    }

    float inv = 1.0f / lsum;
    {
        int q = 32 * wq + l31;
        #pragma unroll
        for (int mt = 0; mt < 2; ++mt) {
            #pragma unroll
            for (int m2 = 0; m2 < 4; ++m2) {
                float4 v4;
                if (mt == 0) {
                    v4.x = acc0[4*m2+0] * inv; v4.y = acc0[4*m2+1] * inv;
                    v4.z = acc0[4*m2+2] * inv; v4.w = acc0[4*m2+3] * inv;
                } else {
                    v4.x = acc1[4*m2+0] * inv; v4.y = acc1[4*m2+1] * inv;
                    v4.z = acc1[4*m2+2] * inv; v4.w = acc1[4*m2+3] * inv;
                }
                int d0 = 4 * hh + 8 * m2 + 32 * mt;
                int ch = (d0 >> 2) ^ (q & 15);
                *(float4*)(smem + q * 256 + ch * 16) = v4;
            }
        }
    }
    __syncthreads();
    {
        const int cl = t >> 4, ln = t & 15;
        #pragma unroll
        for (int rr = 0; rr < 8; ++rr) {
            int row = cl * 8 + rr;
            int ch  = ln ^ (row & 15);
            float4 v4 = *(const float4*)(smem + row * 256 + ch * 16);
            *(float4*)&ctx[((size_t)(blockIdx.z * SEQ) + q0 + row) * HIDDEN
                           + blockIdx.y * HD + 4 * ln] = v4;
        }
    }
}

// ---------------------------------------------------------------------------
extern "C" void kernel_launch(void* const* d_in, const int* in_sizes, int n_in,
                              void* d_out, int out_size, void* d_ws, size_t ws_size,
                              hipStream_t stream)
{
    const float* x     = (const float*)d_in[0];
    const float* w_qkv = (const float*)d_in[1];
    const float* b_qkv = (const float*)d_in[2];
    const float* w_out = (const float*)d_in[3];
    const float* b_out = (const float*)d_in[4];
    float* out = (float*)d_out;

    const size_t PH = (size_t)BATCH * HEADS * SEQ * HD;   // 4,194,304 elems/plane
    unsigned short* ws = (unsigned short*)d_ws;
    // ws layout (64 MB total, same as round 2):
    unsigned short* q_hi  = ws;                 // [0, 4M)
    unsigned short* q_lo  = ws + PH;            // [4M, 8M)
    unsigned short* k_hi  = ws + 2 * PH;
    unsigned short* k_lo  = ws + 3 * PH;
    unsigned short* vt_hi = ws + 4 * PH;
    unsigned short* vt_lo = ws + 5 * PH;        // ends 24M
    unsigned short* wqh   = ws + 6 * PH;        // [24M, 27M)
    unsigned short* wql   = wqh + 3 * PH / 4;   // [27M, 30M)
    unsigned short* woh   = wqh + 6 * PH / 4;   // [30M, 31M)
    unsigned short* wol   = woh + PH / 4;       // [31M, 32M)
    // ct planes recycle dead q planes after attn:
    unsigned short* cth   = ws;
    unsigned short* ctl   = ws + PH;
    // x planes live in d_out until qkv_gemm completes; attn then writes f32
    // ctx over the same region; out_gemm finally writes the real output.
    unsigned short* xh    = (unsigned short*)d_out;
    unsigned short* xl    = xh + PH;
    float* ctxf = (float*)d_out;

    conv_split<<<4096, 256, 0, stream>>>(x, xh, xl);
    conv_split<<<3072, 256, 0, stream>>>(w_qkv, wqh, wql);
    conv_split<<<1024, 256, 0, stream>>>(w_out, woh, wol);
    qkv_gemm<<<dim3(32, 24), 256, 0, stream>>>(xh, xl, wqh, wql, b_qkv,
                                               q_hi, q_lo, k_hi, k_lo, vt_hi, vt_lo);
    attn_mfma<<<dim3(SEQ / 128, HEADS, BATCH), 256, 0, stream>>>(
        q_hi, q_lo, k_hi, k_lo, vt_hi, vt_lo, ctxf);
    conv_split<<<4096, 256, 0, stream>>>(ctxf, cth, ctl);
    out_gemm<<<dim3(32, 8), 256, 0, stream>>>(cth, ctl, woh, wol, b_out, out);
}

// Round 4
// 257.658 us; speedup vs baseline: 3.7963x; 1.0873x over previous
//
#include <hip/hip_runtime.h>
#include <math.h>

#define BATCH 2
#define SEQ   2048
#define HIDDEN 1024
#define HEADS 16
#define HD    64
#define QSCALE 0.18033688011112042f   // log2(e)/8 : scores computed in exp2 domain

typedef __attribute__((ext_vector_type(8)))  short short8;
typedef __attribute__((ext_vector_type(16))) float f32x16;

__device__ __forceinline__ unsigned short f2bf(float f) {
    unsigned int u = __builtin_bit_cast(unsigned int, f);
    u = (u + 0x7FFFu + ((u >> 16) & 1u)) >> 16;   // round-to-nearest-even
    return (unsigned short)u;
}
__device__ __forceinline__ float bf2f(unsigned short h) {
    unsigned int u = ((unsigned int)h) << 16;
    return __builtin_bit_cast(float, u);
}
__device__ __forceinline__ void gl16(const void* g, void* l) {
    __builtin_amdgcn_global_load_lds(
        (const __attribute__((address_space(1))) void*)g,
        (__attribute__((address_space(3))) void*)l,
        16, 0, 0);
}

// ---------------------------------------------------------------------------
// conv_split: f32 -> (hi, lo) bf16 planes.
// ---------------------------------------------------------------------------
__global__ __launch_bounds__(256)
void conv_split(const float* __restrict__ src,
                unsigned short* __restrict__ hi, unsigned short* __restrict__ lo)
{
    int idx = blockIdx.x * 256 + threadIdx.x;
    float4 v = ((const float4*)src)[idx];
    ushort4 h4, l4;
    h4.x = f2bf(v.x); l4.x = f2bf(v.x - bf2f(h4.x));
    h4.y = f2bf(v.y); l4.y = f2bf(v.y - bf2f(h4.y));
    h4.z = f2bf(v.z); l4.z = f2bf(v.z - bf2f(h4.z));
    h4.w = f2bf(v.w); l4.w = f2bf(v.w - bf2f(h4.w));
    ((ushort4*)hi)[idx] = h4;
    ((ushort4*)lo)[idx] = l4;
}

// ---------------------------------------------------------------------------
// Split-bf16 MFMA GEMM core (unchanged from round 3).
// ---------------------------------------------------------------------------
__device__ __forceinline__ void gemm_core(
    const char* Ah, const char* Al, const char* Bh, const char* Bl,
    int m0, int n0, char* smem, f32x16 acc[2][2])
{
    const int t    = threadIdx.x;
    const int lane = t & 63;
    const int w    = t >> 6;
    const int wm   = w >> 1, wn = w & 1;
    const int l31  = lane & 31, hh = lane >> 5;
    const int srow = lane >> 3;
    const int sc   = lane & 7;

    auto stage = [&](int buf, int kt) {
        #pragma unroll
        for (int i = 0; i < 4; ++i) {
            int r = i * 32 + w * 8 + srow;
            int c = sc ^ (r & 7);                    // chunk: 0-3 hi, 4-7 lo
            size_t go = ((size_t)(m0 + r) * 1024 + kt * 32 + (c & 3) * 8) * 2;
            gl16(((c & 4) ? Al : Ah) + go, smem + buf * 32768 + i * 4096 + w * 1024);
            size_t gob = ((size_t)(n0 + r) * 1024 + kt * 32 + (c & 3) * 8) * 2;
            gl16(((c & 4) ? Bl : Bh) + gob, smem + buf * 32768 + 16384 + i * 4096 + w * 1024);
        }
    };

    stage(0, 0);
    __syncthreads();

    for (int kt = 0; kt < 32; ++kt) {
        if (kt + 1 < 32) stage((kt & 1) ^ 1, kt + 1);
        const char* Ab = smem + (kt & 1) * 32768;
        const char* Bb = Ab + 16384;
        #pragma unroll
        for (int ks = 0; ks < 2; ++ks) {
            short8 ah[2], al[2], bh[2], bl[2];
            #pragma unroll
            for (int mt = 0; mt < 2; ++mt) {
                int R  = wm * 64 + mt * 32 + l31;
                int ch = ((ks * 2 + hh) ^ (R & 7)) * 16;
                int cl = ((4 + ks * 2 + hh) ^ (R & 7)) * 16;
                ah[mt] = *(const short8*)(Ab + R * 128 + ch);
                al[mt] = *(const short8*)(Ab + R * 128 + cl);
            }
            #pragma unroll
            for (int nt = 0; nt < 2; ++nt) {
                int R  = wn * 64 + nt * 32 + l31;
                int ch = ((ks * 2 + hh) ^ (R & 7)) * 16;
                int cl = ((4 + ks * 2 + hh) ^ (R & 7)) * 16;
                bh[nt] = *(const short8*)(Bb + R * 128 + ch);
                bl[nt] = *(const short8*)(Bb + R * 128 + cl);
            }
            #pragma unroll
            for (int mt = 0; mt < 2; ++mt)
                #pragma unroll
                for (int nt = 0; nt < 2; ++nt) {
                    acc[mt][nt] = __builtin_amdgcn_mfma_f32_32x32x16_bf16(ah[mt], bh[nt], acc[mt][nt], 0, 0, 0);
                    acc[mt][nt] = __builtin_amdgcn_mfma_f32_32x32x16_bf16(ah[mt], bl[nt], acc[mt][nt], 0, 0, 0);
                    acc[mt][nt] = __builtin_amdgcn_mfma_f32_32x32x16_bf16(al[mt], bh[nt], acc[mt][nt], 0, 0, 0);
                }
        }
        __syncthreads();
    }
}

// ---------------------------------------------------------------------------
// QKV GEMM + scatter epilogue (unchanged from round 3).
// ---------------------------------------------------------------------------
__global__ __launch_bounds__(256, 2)
void qkv_gemm(const unsigned short* __restrict__ xh, const unsigned short* __restrict__ xl,
              const unsigned short* __restrict__ wh, const unsigned short* __restrict__ wl,
              const float* __restrict__ bias,
              unsigned short* __restrict__ q_hi, unsigned short* __restrict__ q_lo,
              unsigned short* __restrict__ k_hi, unsigned short* __restrict__ k_lo,
              unsigned short* __restrict__ vt_hi, unsigned short* __restrict__ vt_lo)
{
    __shared__ char smem[65536];
    f32x16 acc[2][2] = {{{}, {}}, {{}, {}}};
    const int m0 = blockIdx.x * 128, n0 = blockIdx.y * 128;
    gemm_core((const char*)xh, (const char*)xl, (const char*)wh, (const char*)wl,
              m0, n0, smem, acc);

    const int t    = threadIdx.x;
    const int lane = t & 63;
    const int w    = t >> 6;
    const int wm   = w >> 1, wn = w & 1;
    const int l31  = lane & 31, hh = lane >> 5;

    #pragma unroll
    for (int mt = 0; mt < 2; ++mt)
        #pragma unroll
        for (int nt = 0; nt < 2; ++nt) {
            int nl = wn * 64 + nt * 32 + l31;
            #pragma unroll
            for (int r = 0; r < 16; ++r) {
                int ml = wm * 64 + mt * 32 + (r & 3) + 8 * (r >> 2) + 4 * hh;
                *(float*)(smem + ml * 512 + nl * 4) = acc[mt][nt][r];
            }
        }
    __syncthreads();

    const int which = n0 >> 10;
    const int hbase = (n0 & 1023) >> 6;
    const int b     = m0 >> 11;
    const int s0    = m0 & 2047;

    if (which < 2) {
        unsigned short* ph = which ? k_hi : q_hi;
        unsigned short* pl = which ? k_lo : q_lo;
        const float scl = (which == 0) ? QSCALE : 1.0f;
        const int nc = t & 31;
        float4 b4 = *(const float4*)&bias[n0 + nc * 4];
        const int head = hbase + (nc >> 4);
        const int d0   = (nc & 15) * 4;
        #pragma unroll
        for (int it = 0; it < 16; ++it) {
            int m = it * 8 + (t >> 5);
            float4 v = *(const float4*)(smem + m * 512 + nc * 16);
            float r0 = (v.x + b4.x) * scl, r1 = (v.y + b4.y) * scl;
            float r2 = (v.z + b4.z) * scl, r3 = (v.w + b4.w) * scl;
            ushort4 h4, l4;
            h4.x = f2bf(r0); l4.x = f2bf(r0 - bf2f(h4.x));
            h4.y = f2bf(r1); l4.y = f2bf(r1 - bf2f(h4.y));
            h4.z = f2bf(r2); l4.z = f2bf(r2 - bf2f(h4.z));
            h4.w = f2bf(r3); l4.w = f2bf(r3 - bf2f(h4.w));
            size_t idx = (((size_t)(b * HEADS + head)) * SEQ + s0 + m) * HD + d0;
            *(ushort4*)&ph[idx] = h4;
            *(ushort4*)&pl[idx] = l4;
        }
    } else {
        const int nl   = t & 127;
        const float bs = bias[n0 + nl];
        const int head = hbase + (nl >> 6);
        const int d    = nl & 63;
        #pragma unroll
        for (int it = 0; it < 16; ++it) {
            int mq = it * 2 + (t >> 7);
            float r0 = *(const float*)(smem + (mq * 4 + 0) * 512 + nl * 4) + bs;
            float r1 = *(const float*)(smem + (mq * 4 + 1) * 512 + nl * 4) + bs;
            float r2 = *(const float*)(smem + (mq * 4 + 2) * 512 + nl * 4) + bs;
            float r3 = *(const float*)(smem + (mq * 4 + 3) * 512 + nl * 4) + bs;
            ushort4 h4, l4;
            h4.x = f2bf(r0); l4.x = f2bf(r0 - bf2f(h4.x));
            h4.y = f2bf(r1); l4.y = f2bf(r1 - bf2f(h4.y));
            h4.z = f2bf(r2); l4.z = f2bf(r2 - bf2f(h4.z));
            h4.w = f2bf(r3); l4.w = f2bf(r3 - bf2f(h4.w));
            size_t idx = (((size_t)(b * HEADS + head)) * HD + d) * SEQ + s0 + mq * 4;
            *(ushort4*)&vt_hi[idx] = h4;
            *(ushort4*)&vt_lo[idx] = l4;
        }
    }
}

// ---------------------------------------------------------------------------
// Output projection GEMM (unchanged from round 3).
// ---------------------------------------------------------------------------
__global__ __launch_bounds__(256, 2)
void out_gemm(const unsigned short* __restrict__ ah_, const unsigned short* __restrict__ al_,
              const unsigned short* __restrict__ bh_, const unsigned short* __restrict__ bl_,
              const float* __restrict__ bias, float* __restrict__ out)
{
    __shared__ char smem[65536];
    f32x16 acc[2][2] = {{{}, {}}, {{}, {}}};
    const int m0 = blockIdx.x * 128, n0 = blockIdx.y * 128;
    gemm_core((const char*)ah_, (const char*)al_, (const char*)bh_, (const char*)bl_,
              m0, n0, smem, acc);

    const int t    = threadIdx.x;
    const int lane = t & 63;
    const int w    = t >> 6;
    const int wm   = w >> 1, wn = w & 1;
    const int l31  = lane & 31, hh = lane >> 5;

    #pragma unroll
    for (int mt = 0; mt < 2; ++mt)
        #pragma unroll
        for (int nt = 0; nt < 2; ++nt) {
            int n = n0 + wn * 64 + nt * 32 + l31;
            float bb = bias[n];
            #pragma unroll
            for (int r = 0; r < 16; ++r) {
                int m = m0 + wm * 64 + mt * 32 + (r & 3) + 8 * (r >> 2) + 4 * hh;
                out[(size_t)m * 1024 + n] = acc[mt][nt][r] + bb;
            }
        }
}

// ---------------------------------------------------------------------------
// MFMA flash attention. R4 changes: (1) PV drops the P-lo term (2 terms:
// Vhi*Phi + Vlo*Phi) — P-hi is RNE bf16, error ~6e-5 for diffuse softmax;
// (2) LDS shrunk 64K->48K: KV double-buffer #1 overlaps the Q staging
// region (Q hoisted to regs; extra barrier after hoist) -> 3 blocks/CU.
// ---------------------------------------------------------------------------
#define NKT (SEQ / 32)

__global__ __launch_bounds__(256)
void attn_mfma(const unsigned short* __restrict__ q_hi, const unsigned short* __restrict__ q_lo,
               const unsigned short* __restrict__ k_hi, const unsigned short* __restrict__ k_lo,
               const unsigned short* __restrict__ vt_hi, const unsigned short* __restrict__ vt_lo,
               float* __restrict__ ctx)
{
    __shared__ char smem[49152];
    const int t    = threadIdx.x;
    const int lane = t & 63;
    const int wq   = t >> 6;
    const int l31  = lane & 31;
    const int hh   = lane >> 5;
    const int q0   = blockIdx.x * 128;
    const size_t bh = (size_t)(blockIdx.z * HEADS + blockIdx.y);

    const char* qhB = (const char*)(q_hi + bh * SEQ * HD);
    const char* qlB = (const char*)(q_lo + bh * SEQ * HD);
    const char* khB = (const char*)(k_hi + bh * SEQ * HD);
    const char* klB = (const char*)(k_lo + bh * SEQ * HD);
    const char* vhB = (const char*)(vt_hi + bh * SEQ * HD);
    const char* vlB = (const char*)(vt_lo + bh * SEQ * HD);

    // LDS map (48 KB): Q staged at [0,32K) transiently (hoisted to regs).
    // KV buf0: K [32K,40K), V [40K,48K).  KV buf1: K [0,8K), V [8K,16K).
    const int QHI = 0, QLO = 16384;
    const int wbase = wq * 1024;

    {
        int rr = t >> 3, cc = t & 7;
        #pragma unroll
        for (int i = 0; i < 4; ++i) {
            int row = i * 32 + rr;
            int ch  = cc ^ (row & 7);
            gl16(qhB + (size_t)(q0 + row) * 128 + ch * 16, smem + QHI + i * 4096 + wbase);
            gl16(qlB + (size_t)(q0 + row) * 128 + ch * 16, smem + QLO + i * 4096 + wbase);
        }
    }
    auto stageK = [&](int base, int kt) {
        int rr = t >> 3;
        int ch = (t & 7) ^ (rr & 7);
        size_t goff = (size_t)(kt * 32 + rr) * 128 + ch * 16;
        gl16(khB + goff, smem + base +    0 + wbase);
        gl16(klB + goff, smem + base + 4096 + wbase);
    };
    auto stageV = [&](int base, int kt) {
        int rr = t >> 2;
        int s4 = (rr & 3) ^ ((rr >> 2) & 3);
        int ch = (t & 3) ^ s4;
        size_t goff = (size_t)rr * (SEQ * 2) + (size_t)kt * 64 + ch * 16;
        gl16(vhB + goff, smem + base +    0 + wbase);
        gl16(vlB + goff, smem + base + 4096 + wbase);
    };
    stageK(32768, 0);
    stageV(40960, 0);
    __syncthreads();

    short8 qfh[4], qfl[4];
    {
        int qrow = 32 * wq + l31;
        #pragma unroll
        for (int ks = 0; ks < 4; ++ks) {
            int ch = ((2 * ks + hh) ^ (qrow & 7)) * 16;
            qfh[ks] = *(const short8*)(smem + QHI + qrow * 128 + ch);
            qfl[ks] = *(const short8*)(smem + QLO + qrow * 128 + ch);
        }
    }
    __syncthreads();   // protect Q region: buf1 staging overwrites it below

    f32x16 acc0 = {}, acc1 = {};
    float m = -1e30f, lsum = 0.0f;
    int cur = 0;

    for (int kt = 0; kt < NKT; ++kt) {
        if (kt + 1 < NKT) {
            int kb = (cur ^ 1) ? 0    : 32768;
            int vb = (cur ^ 1) ? 8192 : 40960;
            stageK(kb, kt + 1);
            stageV(vb, kt + 1);
        }

        const char* Kh = smem + (cur ? 0 : 32768);
        const char* Kl = Kh + 4096;
        f32x16 sacc = {};
        #pragma unroll
        for (int ks = 0; ks < 4; ++ks) {
            int ch = ((2 * ks + hh) ^ (l31 & 7)) * 16;
            short8 a_h = *(const short8*)(Kh + l31 * 128 + ch);
            short8 a_l = *(const short8*)(Kl + l31 * 128 + ch);
            sacc = __builtin_amdgcn_mfma_f32_32x32x16_bf16(a_h, qfh[ks], sacc, 0, 0, 0);
            sacc = __builtin_amdgcn_mfma_f32_32x32x16_bf16(a_h, qfl[ks], sacc, 0, 0, 0);
            sacc = __builtin_amdgcn_mfma_f32_32x32x16_bf16(a_l, qfh[ks], sacc, 0, 0, 0);
        }

        float pmax = sacc[0];
        #pragma unroll
        for (int i = 1; i < 16; ++i) pmax = fmaxf(pmax, sacc[i]);
        pmax = fmaxf(pmax, __shfl_xor(pmax, 32, 64));
        if (!__all(pmax - m <= 8.0f)) {
            float mn = fmaxf(m, pmax);
            float f  = exp2f(m - mn);
            lsum *= f;
            #pragma unroll
            for (int i = 0; i < 16; ++i) { acc0[i] *= f; acc1[i] *= f; }
            m = mn;
        }
        unsigned int phi[8];
        float psum = 0.0f;
        #pragma unroll
        for (int w = 0; w < 8; ++w) {
            float p0 = exp2f(sacc[2 * w]     - m);
            float p1 = exp2f(sacc[2 * w + 1] - m);
            psum += p0 + p1;
            phi[w] = (unsigned int)f2bf(p0) | ((unsigned int)f2bf(p1) << 16);
        }
        psum += __shfl_xor(psum, 32, 64);
        lsum += psum;

        unsigned int rhi[8];
        #pragma unroll
        for (int w = 0; w < 8; ++w) rhi[w] = __shfl_xor(phi[w], 32, 64);

        const char* Vh = smem + (cur ? 8192 : 40960);
        const char* Vl = Vh + 4096;
        #pragma unroll
        for (int ks = 0; ks < 2; ++ks) {
            uint4 uh;
            if (hh == 0)
                uh = make_uint4(phi[4*ks], phi[4*ks+1], rhi[4*ks], rhi[4*ks+1]);
            else
                uh = make_uint4(rhi[4*ks+2], rhi[4*ks+3], phi[4*ks+2], phi[4*ks+3]);
            short8 pF = __builtin_bit_cast(short8, uh);
            #pragma unroll
            for (int mt = 0; mt < 2; ++mt) {
                int rrow = 32 * mt + l31;
                int s4   = (rrow & 3) ^ ((rrow >> 2) & 3);
                int ch   = ((2 * ks + hh) ^ s4) * 16;
                short8 v_h = *(const short8*)(Vh + rrow * 64 + ch);
                short8 v_l = *(const short8*)(Vl + rrow * 64 + ch);
                if (mt == 0) {
                    acc0 = __builtin_amdgcn_mfma_f32_32x32x16_bf16(v_h, pF, acc0, 0, 0, 0);
                    acc0 = __builtin_amdgcn_mfma_f32_32x32x16_bf16(v_l, pF, acc0, 0, 0, 0);
                } else {
                    acc1 = __builtin_amdgcn_mfma_f32_32x32x16_bf16(v_h, pF, acc1, 0, 0, 0);
                    acc1 = __builtin_amdgcn_mfma_f32_32x32x16_bf16(v_l, pF, acc1, 0, 0, 0);
                }
            }
        }
        __syncthreads();
        cur ^= 1;
    }

    float inv = 1.0f / lsum;
    {
        int q = 32 * wq + l31;
        #pragma unroll
        for (int mt = 0; mt < 2; ++mt) {
            #pragma unroll
            for (int m2 = 0; m2 < 4; ++m2) {
                float4 v4;
                if (mt == 0) {
                    v4.x = acc0[4*m2+0] * inv; v4.y = acc0[4*m2+1] * inv;
                    v4.z = acc0[4*m2+2] * inv; v4.w = acc0[4*m2+3] * inv;
                } else {
                    v4.x = acc1[4*m2+0] * inv; v4.y = acc1[4*m2+1] * inv;
                    v4.z = acc1[4*m2+2] * inv; v4.w = acc1[4*m2+3] * inv;
                }
                int d0 = 4 * hh + 8 * m2 + 32 * mt;
                int ch = (d0 >> 2) ^ (q & 15);
                *(float4*)(smem + q * 256 + ch * 16) = v4;
            }
        }
    }
    __syncthreads();
    {
        const int cl = t >> 4, ln = t & 15;
        #pragma unroll
        for (int rr = 0; rr < 8; ++rr) {
            int row = cl * 8 + rr;
            int ch  = ln ^ (row & 15);
            float4 v4 = *(const float4*)(smem + row * 256 + ch * 16);
            *(float4*)&ctx[((size_t)(blockIdx.z * SEQ) + q0 + row) * HIDDEN
                           + blockIdx.y * HD + 4 * ln] = v4;
        }
    }
}

// ---------------------------------------------------------------------------
extern "C" void kernel_launch(void* const* d_in, const int* in_sizes, int n_in,
                              void* d_out, int out_size, void* d_ws, size_t ws_size,
                              hipStream_t stream)
{
    const float* x     = (const float*)d_in[0];
    const float* w_qkv = (const float*)d_in[1];
    const float* b_qkv = (const float*)d_in[2];
    const float* w_out = (const float*)d_in[3];
    const float* b_out = (const float*)d_in[4];
    float* out = (float*)d_out;

    const size_t PH = (size_t)BATCH * HEADS * SEQ * HD;   // 4,194,304 elems/plane
    unsigned short* ws = (unsigned short*)d_ws;
    unsigned short* q_hi  = ws;
    unsigned short* q_lo  = ws + PH;
    unsigned short* k_hi  = ws + 2 * PH;
    unsigned short* k_lo  = ws + 3 * PH;
    unsigned short* vt_hi = ws + 4 * PH;
    unsigned short* vt_lo = ws + 5 * PH;
    unsigned short* wqh   = ws + 6 * PH;
    unsigned short* wql   = wqh + 3 * PH / 4;
    unsigned short* woh   = wqh + 6 * PH / 4;
    unsigned short* wol   = woh + PH / 4;
    unsigned short* cth   = ws;            // recycle dead q planes after attn
    unsigned short* ctl   = ws + PH;
    unsigned short* xh    = (unsigned short*)d_out;
    unsigned short* xl    = xh + PH;
    float* ctxf = (float*)d_out;

    conv_split<<<4096, 256, 0, stream>>>(x, xh, xl);
    conv_split<<<3072, 256, 0, stream>>>(w_qkv, wqh, wql);
    conv_split<<<1024, 256, 0, stream>>>(w_out, woh, wol);
    qkv_gemm<<<dim3(32, 24), 256, 0, stream>>>(xh, xl, wqh, wql, b_qkv,
                                               q_hi, q_lo, k_hi, k_lo, vt_hi, vt_lo);
    attn_mfma<<<dim3(SEQ / 128, HEADS, BATCH), 256, 0, stream>>>(
        q_hi, q_lo, k_hi, k_lo, vt_hi, vt_lo, ctxf);
    conv_split<<<4096, 256, 0, stream>>>(ctxf, cth, ctl);
    out_gemm<<<dim3(32, 8), 256, 0, stream>>>(cth, ctl, woh, wol, b_out, out);
}

// Round 5
// 170.109 us; speedup vs baseline: 5.7501x; 1.5147x over previous
//
#include <hip/hip_runtime.h>
#include <math.h>

#define BATCH 2
#define SEQ   2048
#define HIDDEN 1024
#define HEADS 16
#define HD    64
#define QSCALE 0.18033688011112042f   // log2(e)/8 : scores computed in exp2 domain

typedef __attribute__((ext_vector_type(8)))  short short8;
typedef __attribute__((ext_vector_type(16))) float f32x16;

__device__ __forceinline__ unsigned short f2bf(float f) {
    unsigned int u = __builtin_bit_cast(unsigned int, f);
    u = (u + 0x7FFFu + ((u >> 16) & 1u)) >> 16;   // round-to-nearest-even
    return (unsigned short)u;
}
__device__ __forceinline__ float bf2f(unsigned short h) {
    unsigned int u = ((unsigned int)h) << 16;
    return __builtin_bit_cast(float, u);
}
__device__ __forceinline__ unsigned int cvt_pk_bf16(float lo, float hi) {
    unsigned int r;
    asm("v_cvt_pk_bf16_f32 %0, %1, %2" : "=v"(r) : "v"(lo), "v"(hi));
    return r;   // bits[15:0]=bf16(lo), bits[31:16]=bf16(hi)
}
__device__ __forceinline__ void gl16(const void* g, void* l) {
    __builtin_amdgcn_global_load_lds(
        (const __attribute__((address_space(1))) void*)g,
        (__attribute__((address_space(3))) void*)l,
        16, 0, 0);
}

// ---------------------------------------------------------------------------
// conv_hi: f32 -> bf16 (hi plane only).
// ---------------------------------------------------------------------------
__global__ __launch_bounds__(256)
void conv_hi(const float* __restrict__ src, unsigned short* __restrict__ hi)
{
    int idx = blockIdx.x * 256 + threadIdx.x;
    float4 v = ((const float4*)src)[idx];
    ushort4 h4;
    h4.x = f2bf(v.x); h4.y = f2bf(v.y); h4.z = f2bf(v.z); h4.w = f2bf(v.w);
    ((ushort4*)hi)[idx] = h4;
}

// ---------------------------------------------------------------------------
// conv_split: f32 -> (hi, lo) bf16 planes (weights only now).
// ---------------------------------------------------------------------------
__global__ __launch_bounds__(256)
void conv_split(const float* __restrict__ src,
                unsigned short* __restrict__ hi, unsigned short* __restrict__ lo)
{
    int idx = blockIdx.x * 256 + threadIdx.x;
    float4 v = ((const float4*)src)[idx];
    ushort4 h4, l4;
    h4.x = f2bf(v.x); l4.x = f2bf(v.x - bf2f(h4.x));
    h4.y = f2bf(v.y); l4.y = f2bf(v.y - bf2f(h4.y));
    h4.z = f2bf(v.z); l4.z = f2bf(v.z - bf2f(h4.z));
    h4.w = f2bf(v.w); l4.w = f2bf(v.w - bf2f(h4.w));
    ((ushort4*)hi)[idx] = h4;
    ((ushort4*)lo)[idx] = l4;
}

// ---------------------------------------------------------------------------
// 2-term split GEMM core: C[128x128] = Ah*(Bh+Bl)^T. A-lo dropped (error
// diluted downstream; see round-5 analysis). BK=32, dbuf 48KB LDS.
// A rows: 64B (4 chunks, hi only). B rows: 128B (8 chunks, hi|lo interleave).
// ---------------------------------------------------------------------------
__device__ __forceinline__ void gemm_core2(
    const char* Ah, const char* Bh, const char* Bl,
    int m0, int n0, char* smem, f32x16 acc[2][2])
{
    const int t    = threadIdx.x;
    const int lane = t & 63;
    const int w    = t >> 6;
    const int wm   = w >> 1, wn = w & 1;
    const int l31  = lane & 31, hh = lane >> 5;

    auto stage = [&](int buf, int kt) {
        // A: 2 issues, rows 64B
        #pragma unroll
        for (int i = 0; i < 2; ++i) {
            int r  = i * 64 + (t >> 2);
            int cs = (t & 3) ^ (r & 3);
            gl16(Ah + ((size_t)(m0 + r) * 1024 + kt * 32 + cs * 8) * 2,
                 smem + buf * 24576 + i * 4096 + w * 1024);
        }
        // B: 4 issues, rows 128B (hi|lo chunks)
        #pragma unroll
        for (int i = 0; i < 4; ++i) {
            int r = i * 32 + (t >> 3);
            int c = (t & 7) ^ (r & 7);
            gl16(((c & 4) ? Bl : Bh) + ((size_t)(n0 + r) * 1024 + kt * 32 + (c & 3) * 8) * 2,
                 smem + buf * 24576 + 8192 + i * 4096 + w * 1024);
        }
    };

    stage(0, 0);
    __syncthreads();

    for (int kt = 0; kt < 32; ++kt) {
        if (kt + 1 < 32) stage((kt & 1) ^ 1, kt + 1);
        const char* Ab = smem + (kt & 1) * 24576;
        const char* Bb = Ab + 8192;
        #pragma unroll
        for (int ks = 0; ks < 2; ++ks) {
            short8 ah[2], bh[2], bl[2];
            #pragma unroll
            for (int mt = 0; mt < 2; ++mt) {
                int R  = wm * 64 + mt * 32 + l31;
                int ch = ((ks * 2 + hh) ^ (R & 3)) * 16;
                ah[mt] = *(const short8*)(Ab + R * 64 + ch);
            }
            #pragma unroll
            for (int nt = 0; nt < 2; ++nt) {
                int R  = wn * 64 + nt * 32 + l31;
                int ch = ((ks * 2 + hh) ^ (R & 7)) * 16;
                int cl = ((4 + ks * 2 + hh) ^ (R & 7)) * 16;
                bh[nt] = *(const short8*)(Bb + R * 128 + ch);
                bl[nt] = *(const short8*)(Bb + R * 128 + cl);
            }
            #pragma unroll
            for (int mt = 0; mt < 2; ++mt)
                #pragma unroll
                for (int nt = 0; nt < 2; ++nt) {
                    acc[mt][nt] = __builtin_amdgcn_mfma_f32_32x32x16_bf16(ah[mt], bh[nt], acc[mt][nt], 0, 0, 0);
                    acc[mt][nt] = __builtin_amdgcn_mfma_f32_32x32x16_bf16(ah[mt], bl[nt], acc[mt][nt], 0, 0, 0);
                }
        }
        __syncthreads();
    }
}

// ---------------------------------------------------------------------------
// QKV GEMM (2-term) + scatter epilogue via bf16 LDS stash (48KB -> 3 blk/CU).
// Emits single-plane bf16 q (pre-scaled), k, and v transposed [bh][d][s].
// ---------------------------------------------------------------------------
__global__ __launch_bounds__(256, 3)
void qkv_gemm(const unsigned short* __restrict__ xh,
              const unsigned short* __restrict__ wh, const unsigned short* __restrict__ wl,
              const float* __restrict__ bias,
              unsigned short* __restrict__ qB, unsigned short* __restrict__ kB,
              unsigned short* __restrict__ vtB)
{
    __shared__ char smem[49152];
    f32x16 acc[2][2] = {{{}, {}}, {{}, {}}};
    const int m0 = blockIdx.x * 128, n0 = blockIdx.y * 128;
    gemm_core2((const char*)xh, (const char*)wh, (const char*)wl, m0, n0, smem, acc);

    const int t    = threadIdx.x;
    const int lane = t & 63;
    const int w    = t >> 6;
    const int wm   = w >> 1, wn = w & 1;
    const int l31  = lane & 31, hh = lane >> 5;

    const int which = n0 >> 10;            // 0=q 1=k 2=v (tiles never straddle)
    const float scl = (which == 0) ? QSCALE : 1.0f;

    // bias+scale+bf16 in regs, stash ushort [128m][stride 272B]
    #pragma unroll
    for (int mt = 0; mt < 2; ++mt)
        #pragma unroll
        for (int nt = 0; nt < 2; ++nt) {
            int nl = wn * 64 + nt * 32 + l31;
            float bb = bias[n0 + nl];
            #pragma unroll
            for (int r = 0; r < 16; ++r) {
                int ml = wm * 64 + mt * 32 + (r & 3) + 8 * (r >> 2) + 4 * hh;
                float val = (acc[mt][nt][r] + bb) * scl;
                *(unsigned short*)(smem + ml * 272 + nl * 2) = f2bf(val);
            }
        }
    __syncthreads();

    const int hbase = (n0 & 1023) >> 6;
    const int b     = m0 >> 11;
    const int s0    = m0 & 2047;

    if (which < 2) {
        unsigned short* pp = which ? kB : qB;
        const int nc   = t & 31;
        const int head = hbase + (nc >> 4);
        const int d0   = (nc & 15) * 4;
        #pragma unroll
        for (int it = 0; it < 16; ++it) {
            int m = it * 8 + (t >> 5);
            ushort4 h4 = *(const ushort4*)(smem + m * 272 + nc * 8);
            size_t idx = (((size_t)(b * HEADS + head)) * SEQ + s0 + m) * HD + d0;
            *(ushort4*)&pp[idx] = h4;
        }
    } else {
        const int nl   = t & 127;
        const int head = hbase + (nl >> 6);
        const int d    = nl & 63;
        #pragma unroll
        for (int it = 0; it < 16; ++it) {
            int mq = it * 2 + (t >> 7);
            ushort4 h4;
            h4.x = *(const unsigned short*)(smem + (mq * 4 + 0) * 272 + nl * 2);
            h4.y = *(const unsigned short*)(smem + (mq * 4 + 1) * 272 + nl * 2);
            h4.z = *(const unsigned short*)(smem + (mq * 4 + 2) * 272 + nl * 2);
            h4.w = *(const unsigned short*)(smem + (mq * 4 + 3) * 272 + nl * 2);
            size_t idx = (((size_t)(b * HEADS + head)) * HD + d) * SEQ + s0 + mq * 4;
            *(ushort4*)&vtB[idx] = h4;
        }
    }
}

// ---------------------------------------------------------------------------
// Output projection GEMM (2-term), f32 epilogue.
// ---------------------------------------------------------------------------
__global__ __launch_bounds__(256, 3)
void out_gemm(const unsigned short* __restrict__ cth,
              const unsigned short* __restrict__ bh_, const unsigned short* __restrict__ bl_,
              const float* __restrict__ bias, float* __restrict__ out)
{
    __shared__ char smem[49152];
    f32x16 acc[2][2] = {{{}, {}}, {{}, {}}};
    const int m0 = blockIdx.x * 128, n0 = blockIdx.y * 128;
    gemm_core2((const char*)cth, (const char*)bh_, (const char*)bl_, m0, n0, smem, acc);

    const int t    = threadIdx.x;
    const int lane = t & 63;
    const int w    = t >> 6;
    const int wm   = w >> 1, wn = w & 1;
    const int l31  = lane & 31, hh = lane >> 5;

    #pragma unroll
    for (int mt = 0; mt < 2; ++mt)
        #pragma unroll
        for (int nt = 0; nt < 2; ++nt) {
            int n = n0 + wn * 64 + nt * 32 + l31;
            float bb = bias[n];
            #pragma unroll
            for (int r = 0; r < 16; ++r) {
                int m = m0 + wm * 64 + mt * 32 + (r & 3) + 8 * (r >> 2) + 4 * hh;
                out[(size_t)m * 1024 + n] = acc[mt][nt][r] + bb;
            }
        }
}

// ---------------------------------------------------------------------------
// Single-bf16 MFMA flash attention. QK 1-term, PV 1-term (error diluted by
// softmax averaging, ~5e-5 at output). P packed via v_cvt_pk_bf16_f32.
// ctx written directly as bf16 [b*s][1024]. LDS 32KB.
// ---------------------------------------------------------------------------
#define NKT (SEQ / 32)

__global__ __launch_bounds__(256, 2)
void attn_mfma(const unsigned short* __restrict__ qB, const unsigned short* __restrict__ kB,
               const unsigned short* __restrict__ vtB, unsigned short* __restrict__ ctxb)
{
    __shared__ char smem[32768];
    const int t    = threadIdx.x;
    const int lane = t & 63;
    const int wq   = t >> 6;
    const int l31  = lane & 31;
    const int hh   = lane >> 5;
    const int q0   = blockIdx.x * 128;
    const size_t bh = (size_t)(blockIdx.z * HEADS + blockIdx.y);

    const char* qP = (const char*)(qB + bh * SEQ * HD);
    const char* kP = (const char*)(kB + bh * SEQ * HD);
    const char* vP = (const char*)(vtB + bh * SEQ * HD);

    // LDS: Q [0,16K) transient; K0@16K V0@20K K1@24K V1@28K (4KB tiles).
    const int wbase = wq * 1024;

    {   // Q: 128 rows x 128B, 4 issues
        int rr = t >> 3, cc = t & 7;
        #pragma unroll
        for (int i = 0; i < 4; ++i) {
            int row = i * 32 + rr;
            int ch  = cc ^ (row & 7);
            gl16(qP + (size_t)(q0 + row) * 128 + ch * 16, smem + i * 4096 + wbase);
        }
    }
    auto stageK = [&](int base, int kt) {
        int rr = t >> 3;
        int ch = (t & 7) ^ (rr & 7);
        gl16(kP + (size_t)(kt * 32 + rr) * 128 + ch * 16, smem + base + wbase);
    };
    auto stageV = [&](int base, int kt) {
        int rr = t >> 2;
        int s4 = (rr & 3) ^ ((rr >> 2) & 3);
        int ch = (t & 3) ^ s4;
        gl16(vP + (size_t)rr * (SEQ * 2) + (size_t)kt * 64 + ch * 16, smem + base + wbase);
    };
    stageK(16384, 0);
    stageV(20480, 0);
    __syncthreads();

    short8 qf[4];
    {
        int qrow = 32 * wq + l31;
        #pragma unroll
        for (int ks = 0; ks < 4; ++ks) {
            int ch = ((2 * ks + hh) ^ (qrow & 7)) * 16;
            qf[ks] = *(const short8*)(smem + qrow * 128 + ch);
        }
    }
    __syncthreads();   // Q region is NOT reused by KV bufs, but hoist must
                       // complete before... (kept: cheap, protects ordering)

    f32x16 acc0 = {}, acc1 = {};
    float m = -1e30f, lsum = 0.0f;
    int cur = 0;

    for (int kt = 0; kt < NKT; ++kt) {
        if (kt + 1 < NKT) {
            stageK(16384 + (cur ^ 1) * 8192, kt + 1);
            stageV(20480 + (cur ^ 1) * 8192, kt + 1);
        }

        // --- S^T = K . Q^T, single term ---
        const char* Kh = smem + 16384 + cur * 8192;
        f32x16 sacc = {};
        #pragma unroll
        for (int ks = 0; ks < 4; ++ks) {
            int ch = ((2 * ks + hh) ^ (l31 & 7)) * 16;
            short8 a_h = *(const short8*)(Kh + l31 * 128 + ch);
            sacc = __builtin_amdgcn_mfma_f32_32x32x16_bf16(a_h, qf[ks], sacc, 0, 0, 0);
        }

        // --- online softmax (lane-local q = l31, partner lane^32) ---
        float pmax = sacc[0];
        #pragma unroll
        for (int i = 1; i < 16; ++i) pmax = fmaxf(pmax, sacc[i]);
        pmax = fmaxf(pmax, __shfl_xor(pmax, 32, 64));
        if (!__all(pmax - m <= 8.0f)) {        // defer-max (exp2 domain)
            float mn = fmaxf(m, pmax);
            float f  = exp2f(m - mn);
            lsum *= f;
            #pragma unroll
            for (int i = 0; i < 16; ++i) { acc0[i] *= f; acc1[i] *= f; }
            m = mn;
        }
        unsigned int phi[8];
        float psum = 0.0f;
        #pragma unroll
        for (int w = 0; w < 8; ++w) {
            float p0 = exp2f(sacc[2 * w]     - m);
            float p1 = exp2f(sacc[2 * w + 1] - m);
            psum += p0 + p1;
            phi[w] = cvt_pk_bf16(p0, p1);
        }
        psum += __shfl_xor(psum, 32, 64);
        lsum += psum;

        unsigned int rhi[8];
        #pragma unroll
        for (int w = 0; w < 8; ++w) rhi[w] = __shfl_xor(phi[w], 32, 64);

        // --- ctx^T += V^T . P^T, single term ---
        const char* Vh = smem + 20480 + cur * 8192;
        #pragma unroll
        for (int ks = 0; ks < 2; ++ks) {
            uint4 uh;
            if (hh == 0)
                uh = make_uint4(phi[4*ks], phi[4*ks+1], rhi[4*ks], rhi[4*ks+1]);
            else
                uh = make_uint4(rhi[4*ks+2], rhi[4*ks+3], phi[4*ks+2], phi[4*ks+3]);
            short8 pF = __builtin_bit_cast(short8, uh);
            #pragma unroll
            for (int mt = 0; mt < 2; ++mt) {
                int rrow = 32 * mt + l31;
                int s4   = (rrow & 3) ^ ((rrow >> 2) & 3);
                int ch   = ((2 * ks + hh) ^ s4) * 16;
                short8 v_h = *(const short8*)(Vh + rrow * 64 + ch);
                if (mt == 0)
                    acc0 = __builtin_amdgcn_mfma_f32_32x32x16_bf16(v_h, pF, acc0, 0, 0, 0);
                else
                    acc1 = __builtin_amdgcn_mfma_f32_32x32x16_bf16(v_h, pF, acc1, 0, 0, 0);
            }
        }
        __syncthreads();
        cur ^= 1;
    }

    // --- epilogue: normalize, bf16, transpose via swizzled LDS, store ---
    float inv = 1.0f / lsum;
    {
        int q = 32 * wq + l31;
        #pragma unroll
        for (int mt = 0; mt < 2; ++mt) {
            #pragma unroll
            for (int m2 = 0; m2 < 4; ++m2) {
                ushort4 h4;
                if (mt == 0) {
                    h4.x = f2bf(acc0[4*m2+0] * inv); h4.y = f2bf(acc0[4*m2+1] * inv);
                    h4.z = f2bf(acc0[4*m2+2] * inv); h4.w = f2bf(acc0[4*m2+3] * inv);
                } else {
                    h4.x = f2bf(acc1[4*m2+0] * inv); h4.y = f2bf(acc1[4*m2+1] * inv);
                    h4.z = f2bf(acc1[4*m2+2] * inv); h4.w = f2bf(acc1[4*m2+3] * inv);
                }
                int d0 = 4 * hh + 8 * m2 + 32 * mt;
                int c  = (d0 >> 3) ^ (q & 7);
                *(ushort4*)(smem + q * 128 + c * 16 + (d0 & 7) * 2) = h4;
            }
        }
    }
    __syncthreads();
    {
        #pragma unroll
        for (int it = 0; it < 4; ++it) {
            int slot = it * 256 + t;
            int row  = slot >> 3;
            int p    = slot & 7;
            uint4 v4 = *(const uint4*)(smem + row * 128 + ((p ^ (row & 7)) * 16));
            *(uint4*)&ctxb[((size_t)(blockIdx.z * SEQ) + q0 + row) * HIDDEN
                           + blockIdx.y * HD + p * 8] = v4;
        }
    }
}

// ---------------------------------------------------------------------------
extern "C" void kernel_launch(void* const* d_in, const int* in_sizes, int n_in,
                              void* d_out, int out_size, void* d_ws, size_t ws_size,
                              hipStream_t stream)
{
    const float* x     = (const float*)d_in[0];
    const float* w_qkv = (const float*)d_in[1];
    const float* b_qkv = (const float*)d_in[2];
    const float* w_out = (const float*)d_in[3];
    const float* b_out = (const float*)d_in[4];
    float* out = (float*)d_out;

    const size_t PH = (size_t)BATCH * HEADS * SEQ * HD;   // 4,194,304 elems/plane
    unsigned short* ws = (unsigned short*)d_ws;
    unsigned short* qB  = ws;                  // 1 plane each, bf16
    unsigned short* kB  = ws + PH;
    unsigned short* vtB = ws + 2 * PH;
    unsigned short* wqh = ws + 3 * PH;
    unsigned short* wql = wqh + 3 * PH / 4;
    unsigned short* woh = wql + 3 * PH / 4;
    unsigned short* wol = woh + PH / 4;
    unsigned short* cth = wol + PH / 4;        // ctx bf16 [B*S][1024]
    unsigned short* xh  = (unsigned short*)d_out;  // x-hi lives in d_out

    conv_hi   <<<4096, 256, 0, stream>>>(x, xh);
    conv_split<<<3072, 256, 0, stream>>>(w_qkv, wqh, wql);
    conv_split<<<1024, 256, 0, stream>>>(w_out, woh, wol);
    qkv_gemm<<<dim3(32, 24), 256, 0, stream>>>(xh, wqh, wql, b_qkv, qB, kB, vtB);
    attn_mfma<<<dim3(SEQ / 128, HEADS, BATCH), 256, 0, stream>>>(qB, kB, vtB, cth);
    out_gemm<<<dim3(32, 8), 256, 0, stream>>>(cth, woh, wol, b_out, out);
}